// Round 15
// baseline (361.576 us; speedup 1.0000x reference)
//
#include <hip/hip_runtime.h>
#include <stdint.h>

#define B_     8
#define LQ_    4096
#define S_     77
#define SP_    80
#define D_     1024
#define H_     16
#define HD_    64
#define NC_    1280   // H_*SP_
#define NSUBJ_ 32

typedef __attribute__((ext_vector_type(4))) float  f4;
typedef __attribute__((ext_vector_type(8))) short  short8;
typedef __attribute__((ext_vector_type(8))) unsigned short us8;
typedef __attribute__((ext_vector_type(4))) unsigned short us4;

__device__ __forceinline__ unsigned short f2bf(float f) {
  union { float f; unsigned u; } x; x.f = f;
  unsigned r = x.u + 0x7FFFu + ((x.u >> 16) & 1u);
  return (unsigned short)(r >> 16);
}
__device__ __forceinline__ float bf2f(unsigned short v) {
  union { unsigned u; float f; } x; x.u = ((unsigned)v) << 16;
  return x.f;
}

__device__ __forceinline__ void gload16(const void* g, void* s) {
  __builtin_amdgcn_global_load_lds((const __attribute__((address_space(1))) void*)g,
                                   (__attribute__((address_space(3))) void*)s, 16, 0, 0);
}

// ---------------- hssum partials + hs -> bf16 convert ----------------
__global__ __launch_bounds__(256) void k_hssum(const float* __restrict__ hs,
                                               float* __restrict__ part,
                                               unsigned short* __restrict__ hsb) {
  int b = blockIdx.y;
  size_t base = ((size_t)b * LQ_ + (size_t)blockIdx.x * 64) * D_ + threadIdx.x * 4;
  f4 acc = {0.f, 0.f, 0.f, 0.f};
  for (int l = 0; l < 64; ++l) {
    f4 v = *(const f4*)(hs + base + (size_t)l * D_);
    acc += v;
    if (hsb) {
      us4 o;
#pragma unroll
      for (int j = 0; j < 4; ++j) o[j] = f2bf(v[j]);
      *(us4*)(hsb + base + (size_t)l * D_) = o;
    }
  }
  *(f4*)(part + (size_t)blockIdx.x * (B_ * D_) + b * D_ + threadIdx.x * 4) = acc;
}

__global__ __launch_bounds__(256) void k_hsred(const float* __restrict__ part,
                                               float* __restrict__ hssum) {
  int i = blockIdx.x * 256 + threadIdx.x;   // [0, 8192)
  float s = 0.f;
  for (int x = 0; x < 64; ++x) s += part[(size_t)x * (B_ * D_) + i];
  hssum[i] = s;
}

// ---------------- k_prep: all small format conversions in ONE launch ----------------
__global__ __launch_bounds__(256) void k_prep(
    const float* __restrict__ Wq, const float* __restrict__ Ak,
    const float* __restrict__ Av, const float* __restrict__ Ao,
    const float* __restrict__ ehs,
    const float* __restrict__ Bk, const float* __restrict__ Bv, const float* __restrict__ Bo,
    unsigned short* __restrict__ wqTb, unsigned short* __restrict__ aTb,
    unsigned short* __restrict__ ehsb, unsigned short* __restrict__ bxb) {
  int z = blockIdx.z;
  int t = threadIdx.x;
  if (z == 4) {
    if (blockIdx.y >= 20) return;            // 640 rows
    int gr = blockIdx.y * 32 + (t >> 3);
    int col = blockIdx.x * 32 + (t & 7) * 4;
    int b = gr / SP_, s = gr - b * SP_;
    us4 o = {0, 0, 0, 0};
    if (s < S_) {
      f4 v = *(const f4*)(ehs + ((size_t)b * S_ + s) * D_ + col);
#pragma unroll
      for (int j = 0; j < 4; ++j) o[j] = f2bf(v[j]);
    }
    *(us4*)(ehsb + (size_t)gr * D_ + col) = o;
    return;
  }
  if (z >= 5) {
    if (blockIdx.x >= 6) return;             // 192 cols
    const float* in = z == 5 ? Bk : (z == 6 ? Bv : Bo);
    unsigned short* outp = bxb + (size_t)(z - 5) * 1024 * 192;
    int rr = blockIdx.y * 32 + (t >> 3);
    int c = blockIdx.x * 32 + (t & 7) * 4;
    f4 v = *(const f4*)(in + (size_t)rr * 192 + c);
    us4 o;
#pragma unroll
    for (int j = 0; j < 4; ++j) o[j] = f2bf(v[j]);
    *(us4*)(outp + (size_t)rr * 192 + c) = o;
    return;
  }
  const float* in = z == 0 ? Wq : (z == 1 ? Ak : (z == 2 ? Av : Ao));
  int R = z == 0 ? 1024 : 192;
  int c0 = blockIdx.x * 32, r0 = blockIdx.y * 32;
  if (r0 >= R) return;
  __shared__ float tile[32][33];
  int tx = t & 31, ty = t >> 5;
#pragma unroll
  for (int k = 0; k < 4; ++k)
    tile[ty + 8 * k][tx] = in[(size_t)(r0 + ty + 8 * k) * 1024 + c0 + tx];
  __syncthreads();
  unsigned short* outp = z == 0 ? wqTb : (aTb + (size_t)(z - 1) * 1024 * 192);
#pragma unroll
  for (int k = 0; k < 4; ++k)
    outp[(size_t)(c0 + ty + 8 * k) * R + r0 + tx] = f2bf(tile[tx][ty + 8 * k]);
}

// ---------------- W_eff = W + LS*(Bx@Ax) -> bf16 wEb. 128x128 tile, BK=64 ----------------
__global__ __launch_bounds__(256) void k_weff_big(
    const unsigned short* __restrict__ bxb, const unsigned short* __restrict__ aTb,
    const float* __restrict__ Wk, const float* __restrict__ Wv, const float* __restrict__ Wo,
    unsigned short* __restrict__ wEb, float alpha) {
  __shared__ short As[128 * 64];
  __shared__ short Bs[128 * 64];
  int z = blockIdx.z;
  const unsigned short* Ab = bxb + (size_t)z * 1024 * 192;
  const unsigned short* Bb = aTb + (size_t)z * 1024 * 192;
  const float* Dm = z == 0 ? Wk : (z == 1 ? Wv : Wo);
  int m0 = blockIdx.x * 128, n0 = blockIdx.y * 128;
  int t = threadIdx.x, lane = t & 63, w = t >> 6;
  int wm = w >> 1, wn = w & 1;
  int r = lane & 15, q = lane >> 4;
  f4 acc[4][4] = {};

  for (int k0 = 0; k0 < 192; k0 += 64) {
    __syncthreads();
#pragma unroll
    for (int p = 0; p < 8; ++p) {
      int cb = p * 256 + w * 64;
      int cc = cb + lane;
      if (cb < 1024) {
        int row = cc >> 3, gc = (cc & 7) ^ (row & 7);
        gload16(Ab + (size_t)(m0 + row) * 192 + k0 + gc * 8, (char*)As + cb * 16);
      } else {
        int bc = cc - 1024, row = bc >> 3, gc = (bc & 7) ^ (row & 7);
        gload16(Bb + (size_t)(n0 + row) * 192 + k0 + gc * 8, (char*)Bs + (cb - 1024) * 16);
      }
    }
    __syncthreads();
#pragma unroll
    for (int kk = 0; kk < 2; ++kk) {
      short8 fa[4], fb[4];
#pragma unroll
      for (int mi = 0; mi < 4; ++mi) {
        int row = wm * 64 + mi * 16 + r;
        fa[mi] = *(const short8*)(As + row * 64 + (((kk * 4 + q) ^ (row & 7)) * 8));
      }
#pragma unroll
      for (int ni = 0; ni < 4; ++ni) {
        int row = wn * 64 + ni * 16 + r;
        fb[ni] = *(const short8*)(Bs + row * 64 + (((kk * 4 + q) ^ (row & 7)) * 8));
      }
#pragma unroll
      for (int mi = 0; mi < 4; ++mi)
#pragma unroll
        for (int ni = 0; ni < 4; ++ni)
          acc[mi][ni] = __builtin_amdgcn_mfma_f32_16x16x32_bf16(fa[mi], fb[ni], acc[mi][ni], 0, 0, 0);
    }
  }
#pragma unroll
  for (int mi = 0; mi < 4; ++mi)
#pragma unroll
    for (int ni = 0; ni < 4; ++ni)
#pragma unroll
      for (int j = 0; j < 4; ++j) {
        int row = m0 + wm * 64 + mi * 16 + q * 4 + j;
        int col = n0 + wn * 64 + ni * 16 + r;
        float val = acc[mi][ni][j] * alpha + Dm[(size_t)row * 1024 + col];
        wEb[(size_t)z * 1048576 + (size_t)row * 1024 + col] = f2bf(val);
      }
}

// ---------------- kv = ehsb @ wEb[k|v]^T  (bf16, 256 blocks, tile 80x64) ----------------
__global__ __launch_bounds__(256) void k_kv(const unsigned short* __restrict__ ehsb,
                                            const unsigned short* __restrict__ wEb,
                                            unsigned short* __restrict__ kvb) {
  __shared__ short As[80 * 64];
  __shared__ short Bs[64 * 64];
  int b = blockIdx.x >> 5, nt = blockIdx.x & 31;
  int n0 = nt * 64;
  const unsigned short* Ab = ehsb + (size_t)b * SP_ * D_;
  int t = threadIdx.x, lane = t & 63, w = t >> 6;
  int r = lane & 15, q = lane >> 4;
  f4 acc[5] = {{0,0,0,0},{0,0,0,0},{0,0,0,0},{0,0,0,0},{0,0,0,0}};

  for (int k0 = 0; k0 < 1024; k0 += 64) {
    __syncthreads();
#pragma unroll
    for (int p = 0; p < 5; ++p) {
      int cb = p * 256 + w * 64;
      if (cb < 1152) {
        int cc = cb + lane;
        if (cb < 640) {
          int row = cc >> 3, gc = (cc & 7) ^ (row & 7);
          gload16(Ab + (size_t)row * D_ + k0 + gc * 8, (char*)As + cb * 16);
        } else {
          int bc = cc - 640, row = bc >> 3, gc = (bc & 7) ^ (row & 7);
          gload16(wEb + (size_t)(n0 + row) * D_ + k0 + gc * 8, (char*)Bs + (cb - 640) * 16);
        }
      }
    }
    __syncthreads();
#pragma unroll
    for (int kk = 0; kk < 2; ++kk) {
      short8 fa[5], fb;
      {
        int row = w * 16 + r;
        fb = *(const short8*)(Bs + row * 64 + (((kk * 4 + q) ^ (row & 7)) * 8));
      }
#pragma unroll
      for (int mi = 0; mi < 5; ++mi) {
        int row = mi * 16 + r;
        fa[mi] = *(const short8*)(As + row * 64 + (((kk * 4 + q) ^ (row & 7)) * 8));
      }
#pragma unroll
      for (int mi = 0; mi < 5; ++mi)
        acc[mi] = __builtin_amdgcn_mfma_f32_16x16x32_bf16(fa[mi], fb, acc[mi], 0, 0, 0);
    }
  }
#pragma unroll
  for (int mi = 0; mi < 5; ++mi)
#pragma unroll
    for (int j = 0; j < 4; ++j) {
      int s = mi * 16 + q * 4 + j;
      int col = n0 + w * 16 + r;
      kvb[((size_t)b * SP_ + s) * 2048 + col] = f2bf(acc[mi][j]);
    }
}

// ---------------- Mt + Ut: one block per (b,h) panel ----------------
__global__ __launch_bounds__(512) void k_mtut(const unsigned short* __restrict__ kvb,
                                              const unsigned short* __restrict__ wqTb,
                                              const unsigned short* __restrict__ wEb,
                                              unsigned short* __restrict__ Mt,
                                              unsigned short* __restrict__ Ut) {
  __shared__ short Ss[80 * 64];
  __shared__ short Ls[256 * 64];
  int z = blockIdx.x;
  bool mt = z < 128;
  int zz = mt ? z : z - 128;
  int b = zz >> 4, h = zz & 15;
  const unsigned short* small_src = kvb + (size_t)b * SP_ * 2048 + (mt ? h * 64 : 1024 + h * 64);
  const unsigned short* large_src = mt ? (wqTb + h * 64) : (wEb + (size_t)2048 * 1024 + h * 64);
  int t = threadIdx.x, lane = t & 63, w = t >> 6;
  int r = lane & 15, q = lane >> 4;

#pragma unroll
  for (int p = 0; p < 2; ++p) {
    int cb = p * 512 + w * 64;
    if (cb < 640) {
      int cc = cb + lane, row = cc >> 3, gc = (cc & 7) ^ (row & 7);
      gload16(small_src + (size_t)row * 2048 + gc * 8, (char*)Ss + cb * 16);
    }
  }

  for (int mc = 0; mc < 4; ++mc) {
    __syncthreads();
#pragma unroll
    for (int p = 0; p < 4; ++p) {
      int cb = p * 512 + w * 64;
      int cc = cb + lane, row = cc >> 3, gc = (cc & 7) ^ (row & 7);
      gload16(large_src + (size_t)(mc * 256 + row) * 1024 + gc * 8, (char*)Ls + cb * 16);
    }
    __syncthreads();

    if (mt) {
      f4 acc[5][2] = {};
#pragma unroll
      for (int kk = 0; kk < 2; ++kk) {
        int co = ((kk * 4 + q) ^ (r & 7)) * 8;
        short8 fa[5], fb[2];
#pragma unroll
        for (int mi = 0; mi < 5; ++mi)
          fa[mi] = *(const short8*)(Ss + (mi * 16 + r) * 64 + co);
#pragma unroll
        for (int ni = 0; ni < 2; ++ni)
          fb[ni] = *(const short8*)(Ls + (w * 32 + ni * 16 + r) * 64 + co);
#pragma unroll
        for (int mi = 0; mi < 5; ++mi)
#pragma unroll
          for (int ni = 0; ni < 2; ++ni)
            acc[mi][ni] = __builtin_amdgcn_mfma_f32_16x16x32_bf16(fa[mi], fb[ni], acc[mi][ni], 0, 0, 0);
      }
#pragma unroll
      for (int mi = 0; mi < 5; ++mi)
#pragma unroll
        for (int ni = 0; ni < 2; ++ni)
#pragma unroll
          for (int j = 0; j < 4; ++j) {
            int s = mi * 16 + q * 4 + j;
            int e = mc * 256 + w * 32 + ni * 16 + r;
            Mt[((size_t)b * NC_ + h * SP_ + s) * 1024 + e] = f2bf(acc[mi][ni][j] * 0.125f);
          }
    } else {
      f4 acc[2][5] = {};
#pragma unroll
      for (int kk = 0; kk < 2; ++kk) {
        int co = ((kk * 4 + q) ^ (r & 7)) * 8;
        short8 fa[2], fb[5];
#pragma unroll
        for (int mi = 0; mi < 2; ++mi)
          fa[mi] = *(const short8*)(Ls + (w * 32 + mi * 16 + r) * 64 + co);
#pragma unroll
        for (int ni = 0; ni < 5; ++ni)
          fb[ni] = *(const short8*)(Ss + (ni * 16 + r) * 64 + co);
#pragma unroll
        for (int mi = 0; mi < 2; ++mi)
#pragma unroll
          for (int ni = 0; ni < 5; ++ni)
            acc[mi][ni] = __builtin_amdgcn_mfma_f32_16x16x32_bf16(fa[mi], fb[ni], acc[mi][ni], 0, 0, 0);
      }
#pragma unroll
      for (int mi = 0; mi < 2; ++mi)
#pragma unroll
        for (int ni = 0; ni < 5; ++ni)
#pragma unroll
          for (int j = 0; j < 4; ++j) {
            int e = mc * 256 + w * 32 + mi * 16 + q * 4 + j;
            int col = h * SP_ + ni * 16 + r;
            Ut[((size_t)b * D_ + e) * NC_ + col] = f2bf(acc[mi][ni][j]);
          }
    }
  }
}

// ---------------- mu/alpha/beta per (b,h,s) ----------------
__global__ void k_mubeta(const float* __restrict__ hssum, const float* __restrict__ Wq,
                         const unsigned short* __restrict__ kvb,
                         const int* __restrict__ sb, const int* __restrict__ sn,
                         const float* __restrict__ csf_p,
                         float* __restrict__ alphav, float* __restrict__ betav) {
  int h = blockIdx.x, b = blockIdx.y;
  int t = threadIdx.x;
  __shared__ float qp[64];
  {
    int hd = t >> 1, half = t & 1;
    const float* wr = Wq + (size_t)(h * 64 + hd) * D_ + half * 512;
    const float* hp = hssum + b * D_ + half * 512;
    float s = 0.f;
    for (int d = 0; d < 512; d += 4) {
      f4 w = *(const f4*)(wr + d);
      f4 x = *(const f4*)(hp + d);
      s += w[0] * x[0] + w[1] * x[1] + w[2] * x[2] + w[3] * x[3];
    }
    s += __shfl_xor(s, 1, 64);
    if (half == 0) qp[hd] = s * (1.f / 4096.f);
  }
  __syncthreads();
  int s = t;
  if (s >= SP_) return;
  const unsigned short* kp = kvb + ((size_t)(b * SP_ + s)) * 2048 + h * HD_;
  float mu = 0.f;
#pragma unroll
  for (int hd = 0; hd < HD_; hd += 4) {
    us4 kv = *(const us4*)(kp + hd);
#pragma unroll
    for (int j = 0; j < 4; ++j) mu += qp[hd + j] * bf2f(kv[j]);
  }
  mu *= 0.125f;
  bool subj = false;
  for (int i = 0; i < NSUBJ_; ++i) subj = subj || (sb[i] == b && sn[i] == s);
  float csf = *csf_p;
  int c = b * NC_ + h * SP_ + s;
  alphav[c] = subj ? csf : 1.f;
  betav[c] = (s >= S_) ? -1e30f : (subj ? -mu * csf : 0.f);
}

// ---------------- score GEMM 256x160, BK=32, 3 bufs (2-tile lead), 2 blocks/CU ----------------
// The untested cell: co-resident blocks fill SIMD during barrier/wait (m114) AND
// counted 2-tile-lead vmcnt keeps each block's stage latency amortized.
// 8 waves = 4M x 2N, wave tile 64x80 (one head per wave, softmax invariant kept).
__global__ __launch_bounds__(512, 4) void k_score_big(
    const unsigned short* __restrict__ hsb, const unsigned short* __restrict__ Mt,
    const float* __restrict__ alphav, const float* __restrict__ betav,
    unsigned short* __restrict__ P) {
  extern __shared__ short lds[];
  const int ASZ = 8192;   // 256x32 shorts
  const int BSZ = 5120;   // 160x32 shorts
  short* B0 = lds + 3 * ASZ;
  int id = blockIdx.x;
  int x = id & 7, idp = id >> 3;
  int nt = idp & 7;                 // 8 n-tiles of 160
  int pid = (idp >> 3) * 8 + x;     // [0,128)
  int b = pid >> 4, mt = pid & 15;
  int m0 = mt * 256, n0 = nt * 160;

  const unsigned short* Ab = hsb + (size_t)b * LQ_ * D_;
  const unsigned short* Bb = Mt + (size_t)b * NC_ * D_;
  const float* alp = alphav + b * NC_;
  const float* bet = betav + b * NC_;
  unsigned short* Pb = P + (size_t)b * LQ_ * NC_;

  int t = threadIdx.x, lane = t & 63, wid = t >> 6;
  int wm = wid >> 1, wn = wid & 1;
  int r = lane & 15, q = lane >> 4;
  f4 acc[4][5] = {};

  auto STAGE = [&](int bf, int k0) {   // wid<2: 4 loads, else 3
#pragma unroll
    for (int p = 0; p < 2; ++p) {      // A: 1024 chunks
      int cb = p * 512 + wid * 64;
      int cc = cb + lane;
      int row = cc >> 2, gc = (cc & 3) ^ ((row >> 1) & 3);
      gload16(Ab + (size_t)(m0 + row) * D_ + k0 + gc * 8, (char*)(lds + bf * ASZ) + cb * 16);
    }
    {                                  // B: chunks 0..511
      int cb = wid * 64;
      int cc = cb + lane;
      int row = cc >> 2, gc = (cc & 3) ^ ((row >> 1) & 3);
      gload16(Bb + (size_t)(n0 + row) * D_ + k0 + gc * 8, (char*)(B0 + bf * BSZ) + cb * 16);
    }
    if (wid < 2) {                     // B: chunks 512..639
      int cb = 512 + wid * 64;
      int cc = cb + lane;
      int row = cc >> 2, gc = (cc & 3) ^ ((row >> 1) & 3);
      gload16(Bb + (size_t)(n0 + row) * D_ + k0 + gc * 8, (char*)(B0 + bf * BSZ) + cb * 16);
    }
  };

  const int T = 32;
  STAGE(0, 0); STAGE(1, 32);
  for (int h = 0; h < T; ++h) {
    int bf = h - (h / 3) * 3;          // h % 3
    if (h + 2 < T) {
      int h2 = h + 2, bf2 = h2 - (h2 / 3) * 3;
      STAGE(bf2, h2 * 32);
      if (wid < 2) asm volatile("s_waitcnt vmcnt(8)" ::: "memory");   // 2 stages in flight
      else         asm volatile("s_waitcnt vmcnt(6)" ::: "memory");
    } else if (h + 1 < T) {
      if (wid < 2) asm volatile("s_waitcnt vmcnt(4)" ::: "memory");
      else         asm volatile("s_waitcnt vmcnt(3)" ::: "memory");
    } else {
      asm volatile("s_waitcnt vmcnt(0)" ::: "memory");
    }
    __builtin_amdgcn_s_barrier();
    const short* Ar = lds + bf * ASZ;
    const short* Br = B0 + bf * BSZ;
    short8 fa[4], fb[5];
#pragma unroll
    for (int ni = 0; ni < 5; ++ni) {
      int row = wn * 80 + ni * 16 + r;
      fb[ni] = *(const short8*)(Br + row * 32 + ((q ^ ((row >> 1) & 3)) * 8));
    }
#pragma unroll
    for (int mi = 0; mi < 4; ++mi) {
      int row = wm * 64 + mi * 16 + r;
      fa[mi] = *(const short8*)(Ar + row * 32 + ((q ^ ((row >> 1) & 3)) * 8));
    }
    __builtin_amdgcn_s_setprio(1);
#pragma unroll
    for (int mi = 0; mi < 4; ++mi)
#pragma unroll
      for (int ni = 0; ni < 5; ++ni)
        acc[mi][ni] = __builtin_amdgcn_mfma_f32_16x16x32_bf16(fa[mi], fb[ni], acc[mi][ni], 0, 0, 0);
    __builtin_amdgcn_s_setprio(0);
    __builtin_amdgcn_s_barrier();      // all waves done reading bf before its re-stage
  }

  // epilogue: alpha*score + beta, per-head softmax (wave owns one 80-col head)
  float al[5], be[5];
#pragma unroll
  for (int ni = 0; ni < 5; ++ni) {
    int cc = n0 + wn * 80 + ni * 16 + r;
    al[ni] = alp[cc]; be[ni] = bet[cc];
  }
#pragma unroll
  for (int mi = 0; mi < 4; ++mi) {
#pragma unroll
    for (int j = 0; j < 4; ++j) {
      float v[5];
      float m = -3.0e38f;
#pragma unroll
      for (int ni = 0; ni < 5; ++ni) { v[ni] = acc[mi][ni][j] * al[ni] + be[ni]; m = fmaxf(m, v[ni]); }
#pragma unroll
      for (int off = 1; off < 16; off <<= 1) m = fmaxf(m, __shfl_xor(m, off, 64));
      float ssum = 0.f;
#pragma unroll
      for (int ni = 0; ni < 5; ++ni) { v[ni] = __expf(v[ni] - m); ssum += v[ni]; }
#pragma unroll
      for (int off = 1; off < 16; off <<= 1) ssum += __shfl_xor(ssum, off, 64);
      float inv = 1.f / ssum;
      int row = m0 + wm * 64 + mi * 16 + q * 4 + j;
      size_t rb = (size_t)row * NC_ + n0 + wn * 80 + r;
#pragma unroll
      for (int ni = 0; ni < 5; ++ni)
        Pb[rb + ni * 16] = f2bf(v[ni] * inv);
    }
  }
}

// ---------------- fallback score GEMM (fp32 A, reg-staged) ----------------
__global__ __launch_bounds__(256) void k_score_f32(
    const float* __restrict__ hs, const unsigned short* __restrict__ Mt,
    const float* __restrict__ alphav, const float* __restrict__ betav,
    unsigned short* __restrict__ P) {
  int id = blockIdx.x;
  int x = id & 7, idp = id >> 3;
  int n_t = idp & 7;
  int pid = (idp >> 3) * 8 + x;
  int b = pid >> 5, m_t = pid & 31;
  int m0 = m_t * 128, n0 = n_t * 160;
  const float* Af = hs + (size_t)b * LQ_ * D_;
  const unsigned short* Bb = Mt + (size_t)b * NC_ * D_;
  const float* alp = alphav + b * NC_;
  const float* bet = betav + b * NC_;
  unsigned short* Pb = P + (size_t)b * LQ_ * NC_;
  __shared__ short As[128 * 64];
  __shared__ short Bs[160 * 64];
  int t = threadIdx.x, lane = t & 63, wid = t >> 6;
  int wm = wid >> 1, wn = wid & 1;
  int srow = lane >> 3;
  int schunk = (lane & 7) ^ srow;
  f4 acc[4][5] = {};
  for (int k0 = 0; k0 < D_; k0 += 64) {
    __syncthreads();
    for (int i = wid; i < 20; i += 4)
      gload16(Bb + (size_t)(n0 + i * 8 + srow) * D_ + k0 + schunk * 8, (char*)Bs + i * 1024);
    int arow = t >> 3, ac = t & 7;
    int awc = ac ^ (arow & 7);
#pragma unroll
    for (int p = 0; p < 4; ++p) {
      int row = p * 32 + arow;
      const float* src = Af + (size_t)(m0 + row) * D_ + k0 + ac * 8;
      f4 v0 = *(const f4*)src;
      f4 v1 = *(const f4*)(src + 4);
      us8 u;
#pragma unroll
      for (int j = 0; j < 4; ++j) { u[j] = f2bf(v0[j]); u[4 + j] = f2bf(v1[j]); }
      *(us8*)(As + row * 64 + awc * 8) = u;
    }
    __syncthreads();
#pragma unroll
    for (int kk = 0; kk < 2; ++kk) {
      int co = ((kk * 4 + (lane >> 4)) ^ (lane & 7)) * 8;
      short8 fa[4], fb[5];
#pragma unroll
      for (int mi = 0; mi < 4; ++mi)
        fa[mi] = *(const short8*)(As + (wm * 64 + mi * 16 + (lane & 15)) * 64 + co);
#pragma unroll
      for (int ni = 0; ni < 5; ++ni)
        fb[ni] = *(const short8*)(Bs + (wn * 80 + ni * 16 + (lane & 15)) * 64 + co);
#pragma unroll
      for (int mi = 0; mi < 4; ++mi)
#pragma unroll
        for (int ni = 0; ni < 5; ++ni)
          acc[mi][ni] = __builtin_amdgcn_mfma_f32_16x16x32_bf16(fa[mi], fb[ni], acc[mi][ni], 0, 0, 0);
    }
  }
  float al[5], be[5];
#pragma unroll
  for (int ni = 0; ni < 5; ++ni) {
    int cc = n0 + wn * 80 + ni * 16 + (lane & 15);
    al[ni] = alp[cc]; be[ni] = bet[cc];
  }
#pragma unroll
  for (int mi = 0; mi < 4; ++mi) {
#pragma unroll
    for (int j = 0; j < 4; ++j) {
      float v[5];
      float m = -3.0e38f;
#pragma unroll
      for (int ni = 0; ni < 5; ++ni) { v[ni] = acc[mi][ni][j] * al[ni] + be[ni]; m = fmaxf(m, v[ni]); }
#pragma unroll
      for (int off = 1; off < 16; off <<= 1) m = fmaxf(m, __shfl_xor(m, off, 64));
      float ssum = 0.f;
#pragma unroll
      for (int ni = 0; ni < 5; ++ni) { v[ni] = __expf(v[ni] - m); ssum += v[ni]; }
#pragma unroll
      for (int off = 1; off < 16; off <<= 1) ssum += __shfl_xor(ssum, off, 64);
      float inv = 1.f / ssum;
      int row = m0 + wm * 64 + mi * 16 + (lane >> 4) * 4 + j;
      size_t rb = (size_t)row * NC_ + n0 + wn * 80 + (lane & 15);
#pragma unroll
      for (int ni = 0; ni < 5; ++ni)
        Pb[rb + ni * 16] = f2bf(v[ni] * inv);
    }
  }
}

// ---------------- out GEMM 256x128, BK=32, 3 bufs (2-tile lead), 2 blocks/CU ----------------
__global__ __launch_bounds__(512, 4) void k_out_big(
    const unsigned short* __restrict__ P, const unsigned short* __restrict__ Ut,
    const float* __restrict__ bo, float* __restrict__ out) {
  extern __shared__ short lds[];
  const int ASZ = 8192;   // 256x32
  const int BSZ = 4096;   // 128x32
  short* B0 = lds + 3 * ASZ;
  int id = blockIdx.x;
  int x = id & 7, idp = id >> 3;
  int nt = idp & 7;                 // 8 n-tiles of 128
  int pid = (idp >> 3) * 8 + x;
  int b = pid >> 4, mt = pid & 15;
  int m0 = mt * 256, n0 = nt * 128;

  const unsigned short* Ab = P + (size_t)b * LQ_ * NC_;
  const unsigned short* Bb = Ut + (size_t)b * D_ * NC_;
  float* ob = out + (size_t)b * LQ_ * D_;

  int t = threadIdx.x, lane = t & 63, wid = t >> 6;
  int wm = wid >> 1, wn = wid & 1;   // wave tile 64x64
  int r = lane & 15, q = lane >> 4;
  f4 acc[4][4] = {};
  const int T = NC_ / 32;   // 40

  auto STAGE = [&](int bf, int k0) {   // 3 loads/thread, uniform
#pragma unroll
    for (int p = 0; p < 2; ++p) {      // A: 1024 chunks
      int cb = p * 512 + wid * 64;
      int cc = cb + lane;
      int row = cc >> 2, gc = (cc & 3) ^ ((row >> 1) & 3);
      gload16(Ab + (size_t)(m0 + row) * NC_ + k0 + gc * 8, (char*)(lds + bf * ASZ) + cb * 16);
    }
    {                                  // B: 512 chunks
      int cb = wid * 64;
      int cc = cb + lane;
      int row = cc >> 2, gc = (cc & 3) ^ ((row >> 1) & 3);
      gload16(Bb + (size_t)(n0 + row) * NC_ + k0 + gc * 8, (char*)(B0 + bf * BSZ) + cb * 16);
    }
  };

  STAGE(0, 0); STAGE(1, 32);
  for (int h = 0; h < T; ++h) {
    int bf = h - (h / 3) * 3;
    if (h + 2 < T) {
      int h2 = h + 2, bf2 = h2 - (h2 / 3) * 3;
      STAGE(bf2, h2 * 32);
      asm volatile("s_waitcnt vmcnt(6)" ::: "memory");
    } else if (h + 1 < T) {
      asm volatile("s_waitcnt vmcnt(3)" ::: "memory");
    } else {
      asm volatile("s_waitcnt vmcnt(0)" ::: "memory");
    }
    __builtin_amdgcn_s_barrier();
    const short* Ar = lds + bf * ASZ;
    const short* Br = B0 + bf * BSZ;
    short8 fa[4], fb[4];
#pragma unroll
    for (int ni = 0; ni < 4; ++ni) {
      int row = wn * 64 + ni * 16 + r;
      fb[ni] = *(const short8*)(Br + row * 32 + ((q ^ ((row >> 1) & 3)) * 8));
    }
#pragma unroll
    for (int mi = 0; mi < 4; ++mi) {
      int row = wm * 64 + mi * 16 + r;
      fa[mi] = *(const short8*)(Ar + row * 32 + ((q ^ ((row >> 1) & 3)) * 8));
    }
    __builtin_amdgcn_s_setprio(1);
#pragma unroll
    for (int mi = 0; mi < 4; ++mi)
#pragma unroll
      for (int ni = 0; ni < 4; ++ni)
        acc[mi][ni] = __builtin_amdgcn_mfma_f32_16x16x32_bf16(fa[mi], fb[ni], acc[mi][ni], 0, 0, 0);
    __builtin_amdgcn_s_setprio(0);
    __builtin_amdgcn_s_barrier();
  }

#pragma unroll
  for (int ni = 0; ni < 4; ++ni) {
    int col = n0 + wn * 64 + ni * 16 + r;
    float bov = bo[col];
#pragma unroll
    for (int mi = 0; mi < 4; ++mi)
#pragma unroll
      for (int j = 0; j < 4; ++j) {
        int row = m0 + wm * 64 + mi * 16 + q * 4 + j;
        ob[(size_t)row * D_ + col] = acc[mi][ni][j] + bov;
      }
  }
}

extern "C" void kernel_launch(void* const* d_in, const int* in_sizes, int n_in,
                              void* d_out, int out_size, void* d_ws, size_t ws_size,
                              hipStream_t stream) {
  const float* hs  = (const float*)d_in[0];
  const float* ehs = (const float*)d_in[1];
  const float* Wq  = (const float*)d_in[2];
  const float* Wk  = (const float*)d_in[3];
  const float* Wv  = (const float*)d_in[4];
  const float* Wo  = (const float*)d_in[5];
  const float* bo  = (const float*)d_in[6];
  const float* Ak  = (const float*)d_in[7];
  const float* Bk  = (const float*)d_in[8];
  const float* Av  = (const float*)d_in[9];
  const float* Bv  = (const float*)d_in[10];
  const float* Ao  = (const float*)d_in[11];
  const float* Bo  = (const float*)d_in[12];
  const float* csf = (const float*)d_in[13];
  const int*   sb  = (const int*)d_in[14];
  const int*   sn  = (const int*)d_in[15];
  float* out = (float*)d_out;

  hipFuncSetAttribute(reinterpret_cast<const void*>(k_score_big),
                      hipFuncAttributeMaxDynamicSharedMemorySize, 79872);
  hipFuncSetAttribute(reinterpret_cast<const void*>(k_out_big),
                      hipFuncAttributeMaxDynamicSharedMemorySize, 73728);

  char* ws = (char*)d_ws;
  unsigned short* P  = (unsigned short*)ws;                   // 83,886,080
  unsigned short* Mt = (unsigned short*)(ws + 83886080);      // 20,971,520
  unsigned short* Ut = (unsigned short*)(ws + 104857600);     // 20,971,520
  const size_t NEED_HSB = 125829120ULL + 67108864ULL + 81920ULL; // 193,019,904
  bool useHsb = ws_size >= NEED_HSB;
  unsigned short* hsb = useHsb ? (unsigned short*)(ws + 125829120) : nullptr;
  char* tail = useHsb ? (ws + 192937984) : (ws + 125829120);
  float* alphav = (float*)tail;
  float* betav  = (float*)(tail + 40960);
  // temporaries overlapped into P's region (all dead before k_score writes P):
  unsigned short* kvb   = (unsigned short*)(ws + 0);          //  2,621,440
  unsigned short* wEb   = (unsigned short*)(ws + 2621440);    //  6,291,456
  unsigned short* wqTb  = (unsigned short*)(ws + 8912896);    //  2,097,152
  unsigned short* aTb   = (unsigned short*)(ws + 11010048);   //  1,179,648
  unsigned short* bxb   = (unsigned short*)(ws + 12189696);   //  1,179,648
  unsigned short* ehsb  = (unsigned short*)(ws + 13369344);   //  1,310,720
  float*          part  = (float*)(ws + 14680064);            //  2,097,152
  float*          hssum = (float*)(ws + 16777216);            //     32,768

  const float LS = 16.0f / 192.0f;

  // hs row-sums (deterministic two-stage) + bf16 conversion of hs
  k_hssum<<<dim3(64, 8), 256, 0, stream>>>(hs, part, hsb);
  k_hsred<<<32, 256, 0, stream>>>(part, hssum);

  // all conversions/transposes in one launch
  k_prep<<<dim3(32, 32, 8), 256, 0, stream>>>(Wq, Ak, Av, Ao, ehs, Bk, Bv, Bo,
                                              wqTb, aTb, ehsb, bxb);

  // W_eff (k,v,o) via proper bf16 GEMM
  k_weff_big<<<dim3(8, 8, 3), 256, 0, stream>>>(bxb, aTb, Wk, Wv, Wo, wEb, LS);

  // kv = ehsb @ wEb[k|v]^T  (bf16, 256 blocks)
  k_kv<<<256, 256, 0, stream>>>(ehsb, wEb, kvb);

  // Mt + Ut panels, one block per (b,h) each
  k_mtut<<<256, 512, 0, stream>>>(kvb, wqTb, wEb, Mt, Ut);

  // per-(b,h,s) column mean (qmean fused) + subject alpha/beta
  k_mubeta<<<dim3(16, 8), 128, 0, stream>>>(hssum, Wq, kvb, sb, sn, csf, alphav, betav);

  // big fused GEMMs: {2 blocks/CU x counted 2-tile-lead} cell
  if (useHsb)
    k_score_big<<<1024, 512, 79872, stream>>>(hsb, Mt, alphav, betav, P);
  else
    k_score_f32<<<2048, 256, 0, stream>>>(hs, Mt, alphav, betav, P);
  k_out_big<<<1024, 512, 73728, stream>>>(P, Ut, bo, out);

  (void)in_sizes; (void)n_in; (void)out_size; (void)ws_size;
}

// Round 16
// 328.796 us; speedup vs baseline: 1.0997x; 1.0997x over previous
//
#include <hip/hip_runtime.h>
#include <stdint.h>

#define B_     8
#define LQ_    4096
#define S_     77
#define SP_    80
#define D_     1024
#define H_     16
#define HD_    64
#define NC_    1280   // H_*SP_
#define NSUBJ_ 32

typedef __attribute__((ext_vector_type(4))) float  f4;
typedef __attribute__((ext_vector_type(8))) short  short8;
typedef __attribute__((ext_vector_type(8))) unsigned short us8;
typedef __attribute__((ext_vector_type(4))) unsigned short us4;

__device__ __forceinline__ unsigned short f2bf(float f) {
  union { float f; unsigned u; } x; x.f = f;
  unsigned r = x.u + 0x7FFFu + ((x.u >> 16) & 1u);
  return (unsigned short)(r >> 16);
}
__device__ __forceinline__ float bf2f(unsigned short v) {
  union { unsigned u; float f; } x; x.u = ((unsigned)v) << 16;
  return x.f;
}

__device__ __forceinline__ void gload16(const void* g, void* s) {
  __builtin_amdgcn_global_load_lds((const __attribute__((address_space(1))) void*)g,
                                   (__attribute__((address_space(3))) void*)s, 16, 0, 0);
}

// ---------------- hssum partials + hs -> bf16 convert ----------------
__global__ __launch_bounds__(256) void k_hssum(const float* __restrict__ hs,
                                               float* __restrict__ part,
                                               unsigned short* __restrict__ hsb) {
  int b = blockIdx.y;
  size_t base = ((size_t)b * LQ_ + (size_t)blockIdx.x * 64) * D_ + threadIdx.x * 4;
  f4 acc = {0.f, 0.f, 0.f, 0.f};
  for (int l = 0; l < 64; ++l) {
    f4 v = *(const f4*)(hs + base + (size_t)l * D_);
    acc += v;
    if (hsb) {
      us4 o;
#pragma unroll
      for (int j = 0; j < 4; ++j) o[j] = f2bf(v[j]);
      *(us4*)(hsb + base + (size_t)l * D_) = o;
    }
  }
  *(f4*)(part + (size_t)blockIdx.x * (B_ * D_) + b * D_ + threadIdx.x * 4) = acc;
}

__global__ __launch_bounds__(256) void k_hsred(const float* __restrict__ part,
                                               float* __restrict__ hssum) {
  int i = blockIdx.x * 256 + threadIdx.x;   // [0, 8192)
  float s = 0.f;
  for (int x = 0; x < 64; ++x) s += part[(size_t)x * (B_ * D_) + i];
  hssum[i] = s;
}

// ---------------- k_prep: all small format conversions in ONE launch ----------------
__global__ __launch_bounds__(256) void k_prep(
    const float* __restrict__ Wq, const float* __restrict__ Ak,
    const float* __restrict__ Av, const float* __restrict__ Ao,
    const float* __restrict__ ehs,
    const float* __restrict__ Bk, const float* __restrict__ Bv, const float* __restrict__ Bo,
    unsigned short* __restrict__ wqTb, unsigned short* __restrict__ aTb,
    unsigned short* __restrict__ ehsb, unsigned short* __restrict__ bxb) {
  int z = blockIdx.z;
  int t = threadIdx.x;
  if (z == 4) {
    if (blockIdx.y >= 20) return;            // 640 rows
    int gr = blockIdx.y * 32 + (t >> 3);
    int col = blockIdx.x * 32 + (t & 7) * 4;
    int b = gr / SP_, s = gr - b * SP_;
    us4 o = {0, 0, 0, 0};
    if (s < S_) {
      f4 v = *(const f4*)(ehs + ((size_t)b * S_ + s) * D_ + col);
#pragma unroll
      for (int j = 0; j < 4; ++j) o[j] = f2bf(v[j]);
    }
    *(us4*)(ehsb + (size_t)gr * D_ + col) = o;
    return;
  }
  if (z >= 5) {
    if (blockIdx.x >= 6) return;             // 192 cols
    const float* in = z == 5 ? Bk : (z == 6 ? Bv : Bo);
    unsigned short* outp = bxb + (size_t)(z - 5) * 1024 * 192;
    int rr = blockIdx.y * 32 + (t >> 3);
    int c = blockIdx.x * 32 + (t & 7) * 4;
    f4 v = *(const f4*)(in + (size_t)rr * 192 + c);
    us4 o;
#pragma unroll
    for (int j = 0; j < 4; ++j) o[j] = f2bf(v[j]);
    *(us4*)(outp + (size_t)rr * 192 + c) = o;
    return;
  }
  const float* in = z == 0 ? Wq : (z == 1 ? Ak : (z == 2 ? Av : Ao));
  int R = z == 0 ? 1024 : 192;
  int c0 = blockIdx.x * 32, r0 = blockIdx.y * 32;
  if (r0 >= R) return;
  __shared__ float tile[32][33];
  int tx = t & 31, ty = t >> 5;
#pragma unroll
  for (int k = 0; k < 4; ++k)
    tile[ty + 8 * k][tx] = in[(size_t)(r0 + ty + 8 * k) * 1024 + c0 + tx];
  __syncthreads();
  unsigned short* outp = z == 0 ? wqTb : (aTb + (size_t)(z - 1) * 1024 * 192);
#pragma unroll
  for (int k = 0; k < 4; ++k)
    outp[(size_t)(c0 + ty + 8 * k) * R + r0 + tx] = f2bf(tile[tx][ty + 8 * k]);
}

// ---------------- W_eff = W + LS*(Bx@Ax) -> bf16 wEb. 128x128 tile, BK=64 ----------------
__global__ __launch_bounds__(256) void k_weff_big(
    const unsigned short* __restrict__ bxb, const unsigned short* __restrict__ aTb,
    const float* __restrict__ Wk, const float* __restrict__ Wv, const float* __restrict__ Wo,
    unsigned short* __restrict__ wEb, float alpha) {
  __shared__ short As[128 * 64];
  __shared__ short Bs[128 * 64];
  int z = blockIdx.z;
  const unsigned short* Ab = bxb + (size_t)z * 1024 * 192;
  const unsigned short* Bb = aTb + (size_t)z * 1024 * 192;
  const float* Dm = z == 0 ? Wk : (z == 1 ? Wv : Wo);
  int m0 = blockIdx.x * 128, n0 = blockIdx.y * 128;
  int t = threadIdx.x, lane = t & 63, w = t >> 6;
  int wm = w >> 1, wn = w & 1;
  int r = lane & 15, q = lane >> 4;
  f4 acc[4][4] = {};

  for (int k0 = 0; k0 < 192; k0 += 64) {
    __syncthreads();
#pragma unroll
    for (int p = 0; p < 8; ++p) {
      int cb = p * 256 + w * 64;
      int cc = cb + lane;
      if (cb < 1024) {
        int row = cc >> 3, gc = (cc & 7) ^ (row & 7);
        gload16(Ab + (size_t)(m0 + row) * 192 + k0 + gc * 8, (char*)As + cb * 16);
      } else {
        int bc = cc - 1024, row = bc >> 3, gc = (bc & 7) ^ (row & 7);
        gload16(Bb + (size_t)(n0 + row) * 192 + k0 + gc * 8, (char*)Bs + (cb - 1024) * 16);
      }
    }
    __syncthreads();
#pragma unroll
    for (int kk = 0; kk < 2; ++kk) {
      short8 fa[4], fb[4];
#pragma unroll
      for (int mi = 0; mi < 4; ++mi) {
        int row = wm * 64 + mi * 16 + r;
        fa[mi] = *(const short8*)(As + row * 64 + (((kk * 4 + q) ^ (row & 7)) * 8));
      }
#pragma unroll
      for (int ni = 0; ni < 4; ++ni) {
        int row = wn * 64 + ni * 16 + r;
        fb[ni] = *(const short8*)(Bs + row * 64 + (((kk * 4 + q) ^ (row & 7)) * 8));
      }
#pragma unroll
      for (int mi = 0; mi < 4; ++mi)
#pragma unroll
        for (int ni = 0; ni < 4; ++ni)
          acc[mi][ni] = __builtin_amdgcn_mfma_f32_16x16x32_bf16(fa[mi], fb[ni], acc[mi][ni], 0, 0, 0);
    }
  }
#pragma unroll
  for (int mi = 0; mi < 4; ++mi)
#pragma unroll
    for (int ni = 0; ni < 4; ++ni)
#pragma unroll
      for (int j = 0; j < 4; ++j) {
        int row = m0 + wm * 64 + mi * 16 + q * 4 + j;
        int col = n0 + wn * 64 + ni * 16 + r;
        float val = acc[mi][ni][j] * alpha + Dm[(size_t)row * 1024 + col];
        wEb[(size_t)z * 1048576 + (size_t)row * 1024 + col] = f2bf(val);
      }
}

// ---------------- kv = ehsb @ wEb[k|v]^T  (bf16, 256 blocks, tile 80x64) ----------------
__global__ __launch_bounds__(256) void k_kv(const unsigned short* __restrict__ ehsb,
                                            const unsigned short* __restrict__ wEb,
                                            unsigned short* __restrict__ kvb) {
  __shared__ short As[80 * 64];
  __shared__ short Bs[64 * 64];
  int b = blockIdx.x >> 5, nt = blockIdx.x & 31;
  int n0 = nt * 64;
  const unsigned short* Ab = ehsb + (size_t)b * SP_ * D_;
  int t = threadIdx.x, lane = t & 63, w = t >> 6;
  int r = lane & 15, q = lane >> 4;
  f4 acc[5] = {{0,0,0,0},{0,0,0,0},{0,0,0,0},{0,0,0,0},{0,0,0,0}};

  for (int k0 = 0; k0 < 1024; k0 += 64) {
    __syncthreads();
#pragma unroll
    for (int p = 0; p < 5; ++p) {
      int cb = p * 256 + w * 64;
      if (cb < 1152) {
        int cc = cb + lane;
        if (cb < 640) {
          int row = cc >> 3, gc = (cc & 7) ^ (row & 7);
          gload16(Ab + (size_t)row * D_ + k0 + gc * 8, (char*)As + cb * 16);
        } else {
          int bc = cc - 640, row = bc >> 3, gc = (bc & 7) ^ (row & 7);
          gload16(wEb + (size_t)(n0 + row) * D_ + k0 + gc * 8, (char*)Bs + (cb - 640) * 16);
        }
      }
    }
    __syncthreads();
#pragma unroll
    for (int kk = 0; kk < 2; ++kk) {
      short8 fa[5], fb;
      {
        int row = w * 16 + r;
        fb = *(const short8*)(Bs + row * 64 + (((kk * 4 + q) ^ (row & 7)) * 8));
      }
#pragma unroll
      for (int mi = 0; mi < 5; ++mi) {
        int row = mi * 16 + r;
        fa[mi] = *(const short8*)(As + row * 64 + (((kk * 4 + q) ^ (row & 7)) * 8));
      }
#pragma unroll
      for (int mi = 0; mi < 5; ++mi)
        acc[mi] = __builtin_amdgcn_mfma_f32_16x16x32_bf16(fa[mi], fb, acc[mi], 0, 0, 0);
    }
  }
#pragma unroll
  for (int mi = 0; mi < 5; ++mi)
#pragma unroll
    for (int j = 0; j < 4; ++j) {
      int s = mi * 16 + q * 4 + j;
      int col = n0 + w * 16 + r;
      kvb[((size_t)b * SP_ + s) * 2048 + col] = f2bf(acc[mi][j]);
    }
}

// ---------------- Mt + Ut: one block per (b,h,mc) — mc split across y ----------------
__global__ __launch_bounds__(512) void k_mtut(const unsigned short* __restrict__ kvb,
                                              const unsigned short* __restrict__ wqTb,
                                              const unsigned short* __restrict__ wEb,
                                              unsigned short* __restrict__ Mt,
                                              unsigned short* __restrict__ Ut) {
  __shared__ short Ss[80 * 64];
  __shared__ short Ls[256 * 64];
  int z = blockIdx.x;
  int mc = blockIdx.y;
  bool mt = z < 128;
  int zz = mt ? z : z - 128;
  int b = zz >> 4, h = zz & 15;
  const unsigned short* small_src = kvb + (size_t)b * SP_ * 2048 + (mt ? h * 64 : 1024 + h * 64);
  const unsigned short* large_src = mt ? (wqTb + h * 64) : (wEb + (size_t)2048 * 1024 + h * 64);
  int t = threadIdx.x, lane = t & 63, w = t >> 6;
  int r = lane & 15, q = lane >> 4;

  // stage small operand (80x64) and this mc's large chunk (256x64)
#pragma unroll
  for (int p = 0; p < 2; ++p) {
    int cb = p * 512 + w * 64;
    if (cb < 640) {
      int cc = cb + lane, row = cc >> 3, gc = (cc & 7) ^ (row & 7);
      gload16(small_src + (size_t)row * 2048 + gc * 8, (char*)Ss + cb * 16);
    }
  }
#pragma unroll
  for (int p = 0; p < 4; ++p) {
    int cb = p * 512 + w * 64;
    int cc = cb + lane, row = cc >> 3, gc = (cc & 7) ^ (row & 7);
    gload16(large_src + (size_t)(mc * 256 + row) * 1024 + gc * 8, (char*)Ls + cb * 16);
  }
  __syncthreads();   // drains vmcnt: Ss + Ls ready

  if (mt) {
    f4 acc[5][2] = {};
#pragma unroll
    for (int kk = 0; kk < 2; ++kk) {
      int co = ((kk * 4 + q) ^ (r & 7)) * 8;
      short8 fa[5], fb[2];
#pragma unroll
      for (int mi = 0; mi < 5; ++mi)
        fa[mi] = *(const short8*)(Ss + (mi * 16 + r) * 64 + co);
#pragma unroll
      for (int ni = 0; ni < 2; ++ni)
        fb[ni] = *(const short8*)(Ls + (w * 32 + ni * 16 + r) * 64 + co);
#pragma unroll
      for (int mi = 0; mi < 5; ++mi)
#pragma unroll
        for (int ni = 0; ni < 2; ++ni)
          acc[mi][ni] = __builtin_amdgcn_mfma_f32_16x16x32_bf16(fa[mi], fb[ni], acc[mi][ni], 0, 0, 0);
    }
#pragma unroll
    for (int mi = 0; mi < 5; ++mi)
#pragma unroll
      for (int ni = 0; ni < 2; ++ni)
#pragma unroll
        for (int j = 0; j < 4; ++j) {
          int s = mi * 16 + q * 4 + j;
          int e = mc * 256 + w * 32 + ni * 16 + r;
          Mt[((size_t)b * NC_ + h * SP_ + s) * 1024 + e] = f2bf(acc[mi][ni][j] * 0.125f);
        }
  } else {
    f4 acc[2][5] = {};
#pragma unroll
    for (int kk = 0; kk < 2; ++kk) {
      int co = ((kk * 4 + q) ^ (r & 7)) * 8;
      short8 fa[2], fb[5];
#pragma unroll
      for (int mi = 0; mi < 2; ++mi)
        fa[mi] = *(const short8*)(Ls + (w * 32 + mi * 16 + r) * 64 + co);
#pragma unroll
      for (int ni = 0; ni < 5; ++ni)
        fb[ni] = *(const short8*)(Ss + (ni * 16 + r) * 64 + co);
#pragma unroll
      for (int mi = 0; mi < 2; ++mi)
#pragma unroll
        for (int ni = 0; ni < 5; ++ni)
          acc[mi][ni] = __builtin_amdgcn_mfma_f32_16x16x32_bf16(fa[mi], fb[ni], acc[mi][ni], 0, 0, 0);
    }
#pragma unroll
    for (int mi = 0; mi < 2; ++mi)
#pragma unroll
      for (int ni = 0; ni < 5; ++ni)
#pragma unroll
        for (int j = 0; j < 4; ++j) {
          int e = mc * 256 + w * 32 + mi * 16 + q * 4 + j;
          int col = h * SP_ + ni * 16 + r;
          Ut[((size_t)b * D_ + e) * NC_ + col] = f2bf(acc[mi][ni][j]);
        }
  }
}

// ---------------- mu/alpha/beta per (b,h,s) ----------------
__global__ void k_mubeta(const float* __restrict__ hssum, const float* __restrict__ Wq,
                         const unsigned short* __restrict__ kvb,
                         const int* __restrict__ sb, const int* __restrict__ sn,
                         const float* __restrict__ csf_p,
                         float* __restrict__ alphav, float* __restrict__ betav) {
  int h = blockIdx.x, b = blockIdx.y;
  int t = threadIdx.x;
  __shared__ float qp[64];
  {
    int hd = t >> 1, half = t & 1;
    const float* wr = Wq + (size_t)(h * 64 + hd) * D_ + half * 512;
    const float* hp = hssum + b * D_ + half * 512;
    float s = 0.f;
    for (int d = 0; d < 512; d += 4) {
      f4 w = *(const f4*)(wr + d);
      f4 x = *(const f4*)(hp + d);
      s += w[0] * x[0] + w[1] * x[1] + w[2] * x[2] + w[3] * x[3];
    }
    s += __shfl_xor(s, 1, 64);
    if (half == 0) qp[hd] = s * (1.f / 4096.f);
  }
  __syncthreads();
  int s = t;
  if (s >= SP_) return;
  const unsigned short* kp = kvb + ((size_t)(b * SP_ + s)) * 2048 + h * HD_;
  float mu = 0.f;
#pragma unroll
  for (int hd = 0; hd < HD_; hd += 4) {
    us4 kv = *(const us4*)(kp + hd);
#pragma unroll
    for (int j = 0; j < 4; ++j) mu += qp[hd + j] * bf2f(kv[j]);
  }
  mu *= 0.125f;
  bool subj = false;
  for (int i = 0; i < NSUBJ_; ++i) subj = subj || (sb[i] == b && sn[i] == s);
  float csf = *csf_p;
  int c = b * NC_ + h * SP_ + s;
  alphav[c] = subj ? csf : 1.f;
  betav[c] = (s >= S_) ? -1e30f : (subj ? -mu * csf : 0.f);
}

// ---------------- score GEMM 256x320 (UNCHANGED from R11/R13 — 110us stable) ----------------
__global__ __launch_bounds__(512, 2) void k_score_big(
    const unsigned short* __restrict__ hsb, const unsigned short* __restrict__ Mt,
    const float* __restrict__ alphav, const float* __restrict__ betav,
    unsigned short* __restrict__ P) {
  extern __shared__ short lds[];
  int id = blockIdx.x;
  int x = id & 7, idp = id >> 3;
  int nt = idp & 3;
  int pid = (idp >> 2) * 8 + x;
  int b = pid >> 4, mt = pid & 15;
  int m0 = mt * 256, n0 = nt * 320;

  const unsigned short* Ab = hsb + (size_t)b * LQ_ * D_;
  const unsigned short* Bb = Mt + (size_t)b * NC_ * D_;
  const float* alp = alphav + b * NC_;
  const float* bet = betav + b * NC_;
  unsigned short* Pb = P + (size_t)b * LQ_ * NC_;

  int t = threadIdx.x, lane = t & 63, wid = t >> 6;
  int wm = wid >> 2, wn = wid & 3;
  int r = lane & 15, q = lane >> 4;
  f4 acc[8][5] = {};

  auto SA = [&](int bf, int k0, int p) {
    int cb = p * 512 + wid * 64;
    int cc = cb + lane;
    int row = cc >> 2, gc = (cc & 3) ^ ((row >> 1) & 3);
    gload16(Ab + (size_t)(m0 + row) * D_ + k0 + gc * 8, (char*)(lds + bf * 8192) + cb * 16);
  };
  auto SB = [&](int bf, int k0, int p) {
    int cb = p * 512 + wid * 64;
    int cc = cb + lane;
    int row = cc >> 2, gc = (cc & 3) ^ ((row >> 1) & 3);
    gload16(Bb + (size_t)(n0 + row) * D_ + k0 + gc * 8, (char*)(lds + 32768 + bf * 10240) + cb * 16);
  };
  auto SBx = [&](int bf, int k0) {
    if (wid < 4) {
      int cb = 1024 + wid * 64;
      int cc = cb + lane;
      int row = cc >> 2, gc = (cc & 3) ^ ((row >> 1) & 3);
      gload16(Bb + (size_t)(n0 + row) * D_ + k0 + gc * 8, (char*)(lds + 32768 + bf * 10240) + cb * 16);
    }
  };
  auto STAGE_P1 = [&](int h) { if (h < 32) { int bf = h & 3, k0 = h * 32; SA(bf, k0, 0); SA(bf, k0, 1); SB(bf, k0, 0); } };
  auto STAGE_P2 = [&](int h) { if (h < 32) { int bf = h & 3, k0 = h * 32; SB(bf, k0, 1); SBx(bf, k0); } };

  STAGE_P1(0); STAGE_P2(0);
  STAGE_P1(1); STAGE_P2(1);
  STAGE_P1(2); STAGE_P2(2);
  if (wid < 4) asm volatile("s_waitcnt vmcnt(10)" ::: "memory");
  else         asm volatile("s_waitcnt vmcnt(8)" ::: "memory");
  __builtin_amdgcn_s_barrier();

#pragma unroll 1
  for (int h = 0; h < 32; ++h) {
    int bf = h & 3;
    const short* Ar = lds + bf * 8192;
    const short* Br = lds + 32768 + bf * 10240;
    short8 fa[4], fb[5];

#pragma unroll
    for (int ni = 0; ni < 5; ++ni) {
      int row = wn * 80 + ni * 16 + r;
      fb[ni] = *(const short8*)(Br + row * 32 + ((q ^ ((row >> 1) & 3)) * 8));
    }
#pragma unroll
    for (int mi = 0; mi < 4; ++mi) {
      int row = wm * 128 + mi * 16 + r;
      fa[mi] = *(const short8*)(Ar + row * 32 + ((q ^ ((row >> 1) & 3)) * 8));
    }
    __builtin_amdgcn_sched_barrier(0);
    STAGE_P1(h + 3);
    __builtin_amdgcn_sched_barrier(0);
    __builtin_amdgcn_s_barrier();
    asm volatile("s_waitcnt lgkmcnt(0)");
    __builtin_amdgcn_s_setprio(1);
#pragma unroll
    for (int mi = 0; mi < 4; ++mi)
#pragma unroll
      for (int ni = 0; ni < 5; ++ni)
        acc[mi][ni] = __builtin_amdgcn_mfma_f32_16x16x32_bf16(fa[mi], fb[ni], acc[mi][ni], 0, 0, 0);
    __builtin_amdgcn_s_setprio(0);

#pragma unroll
    for (int mi = 0; mi < 4; ++mi) {
      int row = wm * 128 + (4 + mi) * 16 + r;
      fa[mi] = *(const short8*)(Ar + row * 32 + ((q ^ ((row >> 1) & 3)) * 8));
    }
    __builtin_amdgcn_sched_barrier(0);
    STAGE_P2(h + 3);
    __builtin_amdgcn_sched_barrier(0);
    __builtin_amdgcn_s_barrier();
    asm volatile("s_waitcnt lgkmcnt(0)");
    __builtin_amdgcn_s_setprio(1);
#pragma unroll
    for (int mi = 0; mi < 4; ++mi)
#pragma unroll
      for (int ni = 0; ni < 5; ++ni)
        acc[4 + mi][ni] = __builtin_amdgcn_mfma_f32_16x16x32_bf16(fa[mi], fb[ni], acc[4 + mi][ni], 0, 0, 0);
    __builtin_amdgcn_s_setprio(0);

    if (h <= 28) {
      if (wid < 4) asm volatile("s_waitcnt vmcnt(10)" ::: "memory");
      else         asm volatile("s_waitcnt vmcnt(8)" ::: "memory");
    } else if (h == 29) {
      if (wid < 4) asm volatile("s_waitcnt vmcnt(5)" ::: "memory");
      else         asm volatile("s_waitcnt vmcnt(4)" ::: "memory");
    } else if (h == 30) {
      asm volatile("s_waitcnt vmcnt(0)" ::: "memory");
    }
    if (h < 31) __builtin_amdgcn_s_barrier();
  }

  float al[5], be[5];
#pragma unroll
  for (int ni = 0; ni < 5; ++ni) {
    int cc = n0 + wn * 80 + ni * 16 + r;
    al[ni] = alp[cc]; be[ni] = bet[cc];
  }
#pragma unroll
  for (int mi = 0; mi < 8; ++mi) {
#pragma unroll
    for (int j = 0; j < 4; ++j) {
      float v[5];
      float m = -3.0e38f;
#pragma unroll
      for (int ni = 0; ni < 5; ++ni) { v[ni] = acc[mi][ni][j] * al[ni] + be[ni]; m = fmaxf(m, v[ni]); }
#pragma unroll
      for (int off = 1; off < 16; off <<= 1) m = fmaxf(m, __shfl_xor(m, off, 64));
      float ssum = 0.f;
#pragma unroll
      for (int ni = 0; ni < 5; ++ni) { v[ni] = __expf(v[ni] - m); ssum += v[ni]; }
#pragma unroll
      for (int off = 1; off < 16; off <<= 1) ssum += __shfl_xor(ssum, off, 64);
      float inv = 1.f / ssum;
      int row = m0 + wm * 128 + mi * 16 + q * 4 + j;
      size_t rb = (size_t)row * NC_ + n0 + wn * 80 + r;
#pragma unroll
      for (int ni = 0; ni < 5; ++ni)
        Pb[rb + ni * 16] = f2bf(v[ni] * inv);
    }
  }
}

// ---------------- fallback score GEMM (fp32 A, reg-staged) ----------------
__global__ __launch_bounds__(256) void k_score_f32(
    const float* __restrict__ hs, const unsigned short* __restrict__ Mt,
    const float* __restrict__ alphav, const float* __restrict__ betav,
    unsigned short* __restrict__ P) {
  int id = blockIdx.x;
  int x = id & 7, idp = id >> 3;
  int n_t = idp & 7;
  int pid = (idp >> 3) * 8 + x;
  int b = pid >> 5, m_t = pid & 31;
  int m0 = m_t * 128, n0 = n_t * 160;
  const float* Af = hs + (size_t)b * LQ_ * D_;
  const unsigned short* Bb = Mt + (size_t)b * NC_ * D_;
  const float* alp = alphav + b * NC_;
  const float* bet = betav + b * NC_;
  unsigned short* Pb = P + (size_t)b * LQ_ * NC_;
  __shared__ short As[128 * 64];
  __shared__ short Bs[160 * 64];
  int t = threadIdx.x, lane = t & 63, wid = t >> 6;
  int wm = wid >> 1, wn = wid & 1;
  int srow = lane >> 3;
  int schunk = (lane & 7) ^ srow;
  f4 acc[4][5] = {};
  for (int k0 = 0; k0 < D_; k0 += 64) {
    __syncthreads();
    for (int i = wid; i < 20; i += 4)
      gload16(Bb + (size_t)(n0 + i * 8 + srow) * D_ + k0 + schunk * 8, (char*)Bs + i * 1024);
    int arow = t >> 3, ac = t & 7;
    int awc = ac ^ (arow & 7);
#pragma unroll
    for (int p = 0; p < 4; ++p) {
      int row = p * 32 + arow;
      const float* src = Af + (size_t)(m0 + row) * D_ + k0 + ac * 8;
      f4 v0 = *(const f4*)src;
      f4 v1 = *(const f4*)(src + 4);
      us8 u;
#pragma unroll
      for (int j = 0; j < 4; ++j) { u[j] = f2bf(v0[j]); u[4 + j] = f2bf(v1[j]); }
      *(us8*)(As + row * 64 + awc * 8) = u;
    }
    __syncthreads();
#pragma unroll
    for (int kk = 0; kk < 2; ++kk) {
      int co = ((kk * 4 + (lane >> 4)) ^ (lane & 7)) * 8;
      short8 fa[4], fb[5];
#pragma unroll
      for (int mi = 0; mi < 4; ++mi)
        fa[mi] = *(const short8*)(As + (wm * 64 + mi * 16 + (lane & 15)) * 64 + co);
#pragma unroll
      for (int ni = 0; ni < 5; ++ni)
        fb[ni] = *(const short8*)(Bs + (wn * 80 + ni * 16 + (lane & 15)) * 64 + co);
#pragma unroll
      for (int mi = 0; mi < 4; ++mi)
#pragma unroll
        for (int ni = 0; ni < 5; ++ni)
          acc[mi][ni] = __builtin_amdgcn_mfma_f32_16x16x32_bf16(fa[mi], fb[ni], acc[mi][ni], 0, 0, 0);
    }
  }
  float al[5], be[5];
#pragma unroll
  for (int ni = 0; ni < 5; ++ni) {
    int cc = n0 + wn * 80 + ni * 16 + (lane & 15);
    al[ni] = alp[cc]; be[ni] = bet[cc];
  }
#pragma unroll
  for (int mi = 0; mi < 4; ++mi) {
#pragma unroll
    for (int j = 0; j < 4; ++j) {
      float v[5];
      float m = -3.0e38f;
#pragma unroll
      for (int ni = 0; ni < 5; ++ni) { v[ni] = acc[mi][ni][j] * al[ni] + be[ni]; m = fmaxf(m, v[ni]); }
#pragma unroll
      for (int off = 1; off < 16; off <<= 1) m = fmaxf(m, __shfl_xor(m, off, 64));
      float ssum = 0.f;
#pragma unroll
      for (int ni = 0; ni < 5; ++ni) { v[ni] = __expf(v[ni] - m); ssum += v[ni]; }
#pragma unroll
      for (int off = 1; off < 16; off <<= 1) ssum += __shfl_xor(ssum, off, 64);
      float inv = 1.f / ssum;
      int row = m0 + wm * 64 + mi * 16 + (lane >> 4) * 4 + j;
      size_t rb = (size_t)row * NC_ + n0 + wn * 80 + (lane & 15);
#pragma unroll
      for (int ni = 0; ni < 5; ++ni)
        Pb[rb + ni * 16] = f2bf(v[ni] * inv);
    }
  }
}

// ---------------- out GEMM 256x256 (UNCHANGED from R11/R13) ----------------
__global__ __launch_bounds__(512, 2) void k_out_big(
    const unsigned short* __restrict__ P, const unsigned short* __restrict__ Ut,
    const float* __restrict__ bo, float* __restrict__ out) {
  extern __shared__ short lds[];
  int id = blockIdx.x;
  int x = id & 7, idp = id >> 3;
  int nt = idp & 3;
  int pid = (idp >> 2) * 8 + x;
  int b = pid >> 4, mt = pid & 15;
  int m0 = mt * 256, n0 = nt * 256;

  const unsigned short* Ab = P + (size_t)b * LQ_ * NC_;
  const unsigned short* Bb = Ut + (size_t)b * D_ * NC_;
  float* ob = out + (size_t)b * LQ_ * D_;

  int t = threadIdx.x, lane = t & 63, wid = t >> 6;
  int wm = wid >> 2, wn = wid & 3;
  int r = lane & 15, q = lane >> 4;
  f4 acc[8][4] = {};
  const int T = NC_ / 32;   // 40

  auto SA = [&](int bf, int k0, int p) {
    int cb = p * 512 + wid * 64;
    int cc = cb + lane;
    int row = cc >> 2, gc = (cc & 3) ^ ((row >> 1) & 3);
    gload16(Ab + (size_t)(m0 + row) * NC_ + k0 + gc * 8, (char*)(lds + bf * 8192) + cb * 16);
  };
  auto SB = [&](int bf, int k0, int p) {
    int cb = p * 512 + wid * 64;
    int cc = cb + lane;
    int row = cc >> 2, gc = (cc & 3) ^ ((row >> 1) & 3);
    gload16(Bb + (size_t)(n0 + row) * NC_ + k0 + gc * 8, (char*)(lds + 32768 + bf * 8192) + cb * 16);
  };
  auto STAGE_P1 = [&](int h) { if (h < T) { int bf = h & 3, k0 = h * 32; SA(bf, k0, 0); SA(bf, k0, 1); } };
  auto STAGE_P2 = [&](int h) { if (h < T) { int bf = h & 3, k0 = h * 32; SB(bf, k0, 0); SB(bf, k0, 1); } };

  STAGE_P1(0); STAGE_P2(0);
  STAGE_P1(1); STAGE_P2(1);
  STAGE_P1(2); STAGE_P2(2);
  asm volatile("s_waitcnt vmcnt(8)" ::: "memory");
  __builtin_amdgcn_s_barrier();

#pragma unroll 1
  for (int h = 0; h < T; ++h) {
    int bf = h & 3;
    const short* Ar = lds + bf * 8192;
    const short* Br = lds + 32768 + bf * 8192;
    short8 fa[4], fb[4];

#pragma unroll
    for (int ni = 0; ni < 4; ++ni) {
      int row = wn * 64 + ni * 16 + r;
      fb[ni] = *(const short8*)(Br + row * 32 + ((q ^ ((row >> 1) & 3)) * 8));
    }
#pragma unroll
    for (int mi = 0; mi < 4; ++mi) {
      int row = wm * 128 + mi * 16 + r;
      fa[mi] = *(const short8*)(Ar + row * 32 + ((q ^ ((row >> 1) & 3)) * 8));
    }
    __builtin_amdgcn_sched_barrier(0);
    STAGE_P1(h + 3);
    __builtin_amdgcn_sched_barrier(0);
    __builtin_amdgcn_s_barrier();
    asm volatile("s_waitcnt lgkmcnt(0)");
    __builtin_amdgcn_s_setprio(1);
#pragma unroll
    for (int mi = 0; mi < 4; ++mi)
#pragma unroll
      for (int ni = 0; ni < 4; ++ni)
        acc[mi][ni] = __builtin_amdgcn_mfma_f32_16x16x32_bf16(fa[mi], fb[ni], acc[mi][ni], 0, 0, 0);
    __builtin_amdgcn_s_setprio(0);

#pragma unroll
    for (int mi = 0; mi < 4; ++mi) {
      int row = wm * 128 + (4 + mi) * 16 + r;
      fa[mi] = *(const short8*)(Ar + row * 32 + ((q ^ ((row >> 1) & 3)) * 8));
    }
    __builtin_amdgcn_sched_barrier(0);
    STAGE_P2(h + 3);
    __builtin_amdgcn_sched_barrier(0);
    __builtin_amdgcn_s_barrier();
    asm volatile("s_waitcnt lgkmcnt(0)");
    __builtin_amdgcn_s_setprio(1);
#pragma unroll
    for (int mi = 0; mi < 4; ++mi)
#pragma unroll
      for (int ni = 0; ni < 4; ++ni)
        acc[4 + mi][ni] = __builtin_amdgcn_mfma_f32_16x16x32_bf16(fa[mi], fb[ni], acc[4 + mi][ni], 0, 0, 0);
    __builtin_amdgcn_s_setprio(0);

    if (h <= T - 4) {
      asm volatile("s_waitcnt vmcnt(8)" ::: "memory");
    } else if (h == T - 3) {
      asm volatile("s_waitcnt vmcnt(4)" ::: "memory");
    } else if (h == T - 2) {
      asm volatile("s_waitcnt vmcnt(0)" ::: "memory");
    }
    if (h < T - 1) __builtin_amdgcn_s_barrier();
  }

#pragma unroll
  for (int ni = 0; ni < 4; ++ni) {
    int col = n0 + wn * 64 + ni * 16 + r;
    float bov = bo[col];
#pragma unroll
    for (int mi = 0; mi < 8; ++mi)
#pragma unroll
      for (int j = 0; j < 4; ++j) {
        int row = m0 + wm * 128 + mi * 16 + q * 4 + j;
        ob[(size_t)row * D_ + col] = acc[mi][ni][j] + bov;
      }
  }
}

extern "C" void kernel_launch(void* const* d_in, const int* in_sizes, int n_in,
                              void* d_out, int out_size, void* d_ws, size_t ws_size,
                              hipStream_t stream) {
  const float* hs  = (const float*)d_in[0];
  const float* ehs = (const float*)d_in[1];
  const float* Wq  = (const float*)d_in[2];
  const float* Wk  = (const float*)d_in[3];
  const float* Wv  = (const float*)d_in[4];
  const float* Wo  = (const float*)d_in[5];
  const float* bo  = (const float*)d_in[6];
  const float* Ak  = (const float*)d_in[7];
  const float* Bk  = (const float*)d_in[8];
  const float* Av  = (const float*)d_in[9];
  const float* Bv  = (const float*)d_in[10];
  const float* Ao  = (const float*)d_in[11];
  const float* Bo  = (const float*)d_in[12];
  const float* csf = (const float*)d_in[13];
  const int*   sb  = (const int*)d_in[14];
  const int*   sn  = (const int*)d_in[15];
  float* out = (float*)d_out;

  hipFuncSetAttribute(reinterpret_cast<const void*>(k_score_big),
                      hipFuncAttributeMaxDynamicSharedMemorySize, 147456);
  hipFuncSetAttribute(reinterpret_cast<const void*>(k_out_big),
                      hipFuncAttributeMaxDynamicSharedMemorySize, 131072);

  char* ws = (char*)d_ws;
  unsigned short* P  = (unsigned short*)ws;                   // 83,886,080
  unsigned short* Mt = (unsigned short*)(ws + 83886080);      // 20,971,520
  unsigned short* Ut = (unsigned short*)(ws + 104857600);     // 20,971,520
  const size_t NEED_HSB = 125829120ULL + 67108864ULL + 81920ULL; // 193,019,904
  bool useHsb = ws_size >= NEED_HSB;
  unsigned short* hsb = useHsb ? (unsigned short*)(ws + 125829120) : nullptr;
  char* tail = useHsb ? (ws + 192937984) : (ws + 125829120);
  float* alphav = (float*)tail;
  float* betav  = (float*)(tail + 40960);
  // temporaries overlapped into P's region (all dead before k_score writes P):
  unsigned short* kvb   = (unsigned short*)(ws + 0);          //  2,621,440
  unsigned short* wEb   = (unsigned short*)(ws + 2621440);    //  6,291,456
  unsigned short* wqTb  = (unsigned short*)(ws + 8912896);    //  2,097,152
  unsigned short* aTb   = (unsigned short*)(ws + 11010048);   //  1,179,648
  unsigned short* bxb   = (unsigned short*)(ws + 12189696);   //  1,179,648
  unsigned short* ehsb  = (unsigned short*)(ws + 13369344);   //  1,310,720
  float*          part  = (float*)(ws + 14680064);            //  2,097,152
  float*          hssum = (float*)(ws + 16777216);            //     32,768

  const float LS = 16.0f / 192.0f;

  // hs row-sums (deterministic two-stage) + bf16 conversion of hs
  k_hssum<<<dim3(64, 8), 256, 0, stream>>>(hs, part, hsb);
  k_hsred<<<32, 256, 0, stream>>>(part, hssum);

  // all conversions/transposes in one launch
  k_prep<<<dim3(32, 32, 8), 256, 0, stream>>>(Wq, Ak, Av, Ao, ehs, Bk, Bv, Bo,
                                              wqTb, aTb, ehsb, bxb);

  // W_eff (k,v,o) via proper bf16 GEMM
  k_weff_big<<<dim3(8, 8, 3), 256, 0, stream>>>(bxb, aTb, Wk, Wv, Wo, wEb, LS);

  // kv = ehsb @ wEb[k|v]^T  (bf16, 256 blocks)
  k_kv<<<256, 256, 0, stream>>>(ehsb, wEb, kvb);

  // Mt + Ut panels: (b,h) x mc chunk, 1024 blocks
  k_mtut<<<dim3(256, 4), 512, 0, stream>>>(kvb, wqTb, wEb, Mt, Ut);

  // per-(b,h,s) column mean (qmean fused) + subject alpha/beta
  k_mubeta<<<dim3(16, 8), 128, 0, stream>>>(hssum, Wq, kvb, sb, sn, csf, alphav, betav);

  // big fused GEMMs (R11/R13 proven versions)
  if (useHsb)
    k_score_big<<<512, 512, 147456, stream>>>(hsb, Mt, alphav, betav, P);
  else
    k_score_f32<<<2048, 256, 0, stream>>>(hs, Mt, alphav, betav, P);
  k_out_big<<<512, 512, 131072, stream>>>(P, Ut, bo, out);

  (void)in_sizes; (void)n_in; (void)out_size; (void)ws_size;
}

// Round 17
// 325.746 us; speedup vs baseline: 1.1100x; 1.0094x over previous
//
#include <hip/hip_runtime.h>
#include <stdint.h>

#define B_     8
#define LQ_    4096
#define S_     77
#define SP_    80
#define D_     1024
#define H_     16
#define HD_    64
#define NC_    1280   // H_*SP_
#define NSUBJ_ 32

typedef __attribute__((ext_vector_type(4))) float  f4;
typedef __attribute__((ext_vector_type(8))) short  short8;
typedef __attribute__((ext_vector_type(8))) unsigned short us8;
typedef __attribute__((ext_vector_type(4))) unsigned short us4;

__device__ __forceinline__ unsigned short f2bf(float f) {
  union { float f; unsigned u; } x; x.f = f;
  unsigned r = x.u + 0x7FFFu + ((x.u >> 16) & 1u);
  return (unsigned short)(r >> 16);
}
__device__ __forceinline__ float bf2f(unsigned short v) {
  union { unsigned u; float f; } x; x.u = ((unsigned)v) << 16;
  return x.f;
}

__device__ __forceinline__ void gload16(const void* g, void* s) {
  __builtin_amdgcn_global_load_lds((const __attribute__((address_space(1))) void*)g,
                                   (__attribute__((address_space(3))) void*)s, 16, 0, 0);
}

// ---------------- hssum partials + hs -> bf16 convert ----------------
__global__ __launch_bounds__(256) void k_hssum(const float* __restrict__ hs,
                                               float* __restrict__ part,
                                               unsigned short* __restrict__ hsb) {
  int b = blockIdx.y;
  size_t base = ((size_t)b * LQ_ + (size_t)blockIdx.x * 64) * D_ + threadIdx.x * 4;
  f4 acc = {0.f, 0.f, 0.f, 0.f};
  for (int l = 0; l < 64; ++l) {
    f4 v = *(const f4*)(hs + base + (size_t)l * D_);
    acc += v;
    if (hsb) {
      us4 o;
#pragma unroll
      for (int j = 0; j < 4; ++j) o[j] = f2bf(v[j]);
      *(us4*)(hsb + base + (size_t)l * D_) = o;
    }
  }
  *(f4*)(part + (size_t)blockIdx.x * (B_ * D_) + b * D_ + threadIdx.x * 4) = acc;
}

__global__ __launch_bounds__(256) void k_hsred(const float* __restrict__ part,
                                               float* __restrict__ hssum) {
  int i = blockIdx.x * 256 + threadIdx.x;   // [0, 8192)
  float s = 0.f;
  for (int x = 0; x < 64; ++x) s += part[(size_t)x * (B_ * D_) + i];
  hssum[i] = s;
}

// ---------------- k_prep: all small format conversions in ONE launch ----------------
__global__ __launch_bounds__(256) void k_prep(
    const float* __restrict__ Wq, const float* __restrict__ Ak,
    const float* __restrict__ Av, const float* __restrict__ Ao,
    const float* __restrict__ ehs,
    const float* __restrict__ Bk, const float* __restrict__ Bv, const float* __restrict__ Bo,
    unsigned short* __restrict__ wqTb, unsigned short* __restrict__ aTb,
    unsigned short* __restrict__ ehsb, unsigned short* __restrict__ bxb) {
  int z = blockIdx.z;
  int t = threadIdx.x;
  if (z == 4) {
    if (blockIdx.y >= 20) return;            // 640 rows
    int gr = blockIdx.y * 32 + (t >> 3);
    int col = blockIdx.x * 32 + (t & 7) * 4;
    int b = gr / SP_, s = gr - b * SP_;
    us4 o = {0, 0, 0, 0};
    if (s < S_) {
      f4 v = *(const f4*)(ehs + ((size_t)b * S_ + s) * D_ + col);
#pragma unroll
      for (int j = 0; j < 4; ++j) o[j] = f2bf(v[j]);
    }
    *(us4*)(ehsb + (size_t)gr * D_ + col) = o;
    return;
  }
  if (z >= 5) {
    if (blockIdx.x >= 6) return;             // 192 cols
    const float* in = z == 5 ? Bk : (z == 6 ? Bv : Bo);
    unsigned short* outp = bxb + (size_t)(z - 5) * 1024 * 192;
    int rr = blockIdx.y * 32 + (t >> 3);
    int c = blockIdx.x * 32 + (t & 7) * 4;
    f4 v = *(const f4*)(in + (size_t)rr * 192 + c);
    us4 o;
#pragma unroll
    for (int j = 0; j < 4; ++j) o[j] = f2bf(v[j]);
    *(us4*)(outp + (size_t)rr * 192 + c) = o;
    return;
  }
  const float* in = z == 0 ? Wq : (z == 1 ? Ak : (z == 2 ? Av : Ao));
  int R = z == 0 ? 1024 : 192;
  int c0 = blockIdx.x * 32, r0 = blockIdx.y * 32;
  if (r0 >= R) return;
  __shared__ float tile[32][33];
  int tx = t & 31, ty = t >> 5;
#pragma unroll
  for (int k = 0; k < 4; ++k)
    tile[ty + 8 * k][tx] = in[(size_t)(r0 + ty + 8 * k) * 1024 + c0 + tx];
  __syncthreads();
  unsigned short* outp = z == 0 ? wqTb : (aTb + (size_t)(z - 1) * 1024 * 192);
#pragma unroll
  for (int k = 0; k < 4; ++k)
    outp[(size_t)(c0 + ty + 8 * k) * R + r0 + tx] = f2bf(tile[tx][ty + 8 * k]);
}

// ---------------- W_eff = W + LS*(Bx@Ax) -> bf16 wEb. 128x128 tile, BK=64 ----------------
__global__ __launch_bounds__(256) void k_weff_big(
    const unsigned short* __restrict__ bxb, const unsigned short* __restrict__ aTb,
    const float* __restrict__ Wk, const float* __restrict__ Wv, const float* __restrict__ Wo,
    unsigned short* __restrict__ wEb, float alpha) {
  __shared__ short As[128 * 64];
  __shared__ short Bs[128 * 64];
  int z = blockIdx.z;
  const unsigned short* Ab = bxb + (size_t)z * 1024 * 192;
  const unsigned short* Bb = aTb + (size_t)z * 1024 * 192;
  const float* Dm = z == 0 ? Wk : (z == 1 ? Wv : Wo);
  int m0 = blockIdx.x * 128, n0 = blockIdx.y * 128;
  int t = threadIdx.x, lane = t & 63, w = t >> 6;
  int wm = w >> 1, wn = w & 1;
  int r = lane & 15, q = lane >> 4;
  f4 acc[4][4] = {};

  for (int k0 = 0; k0 < 192; k0 += 64) {
    __syncthreads();
#pragma unroll
    for (int p = 0; p < 8; ++p) {
      int cb = p * 256 + w * 64;
      int cc = cb + lane;
      if (cb < 1024) {
        int row = cc >> 3, gc = (cc & 7) ^ (row & 7);
        gload16(Ab + (size_t)(m0 + row) * 192 + k0 + gc * 8, (char*)As + cb * 16);
      } else {
        int bc = cc - 1024, row = bc >> 3, gc = (bc & 7) ^ (row & 7);
        gload16(Bb + (size_t)(n0 + row) * 192 + k0 + gc * 8, (char*)Bs + (cb - 1024) * 16);
      }
    }
    __syncthreads();
#pragma unroll
    for (int kk = 0; kk < 2; ++kk) {
      short8 fa[4], fb[4];
#pragma unroll
      for (int mi = 0; mi < 4; ++mi) {
        int row = wm * 64 + mi * 16 + r;
        fa[mi] = *(const short8*)(As + row * 64 + (((kk * 4 + q) ^ (row & 7)) * 8));
      }
#pragma unroll
      for (int ni = 0; ni < 4; ++ni) {
        int row = wn * 64 + ni * 16 + r;
        fb[ni] = *(const short8*)(Bs + row * 64 + (((kk * 4 + q) ^ (row & 7)) * 8));
      }
#pragma unroll
      for (int mi = 0; mi < 4; ++mi)
#pragma unroll
        for (int ni = 0; ni < 4; ++ni)
          acc[mi][ni] = __builtin_amdgcn_mfma_f32_16x16x32_bf16(fa[mi], fb[ni], acc[mi][ni], 0, 0, 0);
    }
  }
#pragma unroll
  for (int mi = 0; mi < 4; ++mi)
#pragma unroll
    for (int ni = 0; ni < 4; ++ni)
#pragma unroll
      for (int j = 0; j < 4; ++j) {
        int row = m0 + wm * 64 + mi * 16 + q * 4 + j;
        int col = n0 + wn * 64 + ni * 16 + r;
        float val = acc[mi][ni][j] * alpha + Dm[(size_t)row * 1024 + col];
        wEb[(size_t)z * 1048576 + (size_t)row * 1024 + col] = f2bf(val);
      }
}

// ---------------- kv = ehsb @ wEb[k|v]^T  (bf16, 256 blocks, 80x64, dbuf) ----------------
// 2-phase counted-vmcnt double-buffer (R4-proven): stage(t+1) before compute(t),
// wave-dependent counted wait (waves 0-1 issue 5 loads/stage, waves 2-3 issue 4).
__global__ __launch_bounds__(256) void k_kv(const unsigned short* __restrict__ ehsb,
                                            const unsigned short* __restrict__ wEb,
                                            unsigned short* __restrict__ kvb) {
  __shared__ short As[2][80 * 64];
  __shared__ short Bs[2][64 * 64];
  int b = blockIdx.x >> 5, nt = blockIdx.x & 31;
  int n0 = nt * 64;
  const unsigned short* Ab = ehsb + (size_t)b * SP_ * D_;
  int t = threadIdx.x, lane = t & 63, w = t >> 6;
  int r = lane & 15, q = lane >> 4;
  f4 acc[5] = {{0,0,0,0},{0,0,0,0},{0,0,0,0},{0,0,0,0},{0,0,0,0}};

  auto STAGE = [&](int bf, int k0) {
#pragma unroll
    for (int p = 0; p < 5; ++p) {
      int cb = p * 256 + w * 64;
      if (cb < 1152) {
        int cc = cb + lane;
        if (cb < 640) {
          int row = cc >> 3, gc = (cc & 7) ^ (row & 7);
          gload16(Ab + (size_t)row * D_ + k0 + gc * 8, (char*)&As[bf][0] + cb * 16);
        } else {
          int bc = cc - 640, row = bc >> 3, gc = (bc & 7) ^ (row & 7);
          gload16(wEb + (size_t)(n0 + row) * D_ + k0 + gc * 8, (char*)&Bs[bf][0] + (cb - 640) * 16);
        }
      }
    }
  };

  STAGE(0, 0);
  int cur = 0;
  for (int kt = 0; kt < 16; ++kt) {
    if (kt < 15) {
      STAGE(cur ^ 1, (kt + 1) * 64);
      if (w < 2) asm volatile("s_waitcnt vmcnt(5)" ::: "memory");   // tile kt complete
      else       asm volatile("s_waitcnt vmcnt(4)" ::: "memory");
    } else {
      asm volatile("s_waitcnt vmcnt(0)" ::: "memory");
    }
    __builtin_amdgcn_s_barrier();
#pragma unroll
    for (int kk = 0; kk < 2; ++kk) {
      short8 fa[5], fb;
      {
        int row = w * 16 + r;
        fb = *(const short8*)(&Bs[cur][0] + row * 64 + (((kk * 4 + q) ^ (row & 7)) * 8));
      }
#pragma unroll
      for (int mi = 0; mi < 5; ++mi) {
        int row = mi * 16 + r;
        fa[mi] = *(const short8*)(&As[cur][0] + row * 64 + (((kk * 4 + q) ^ (row & 7)) * 8));
      }
#pragma unroll
      for (int mi = 0; mi < 5; ++mi)
        acc[mi] = __builtin_amdgcn_mfma_f32_16x16x32_bf16(fa[mi], fb, acc[mi], 0, 0, 0);
    }
    __builtin_amdgcn_s_barrier();
    cur ^= 1;
  }
#pragma unroll
  for (int mi = 0; mi < 5; ++mi)
#pragma unroll
    for (int j = 0; j < 4; ++j) {
      int s = mi * 16 + q * 4 + j;
      int col = n0 + w * 16 + r;
      kvb[((size_t)b * SP_ + s) * 2048 + col] = f2bf(acc[mi][j]);
    }
}

// ---------------- Mt + Ut: one block per (b,h,mc) ----------------
__global__ __launch_bounds__(512) void k_mtut(const unsigned short* __restrict__ kvb,
                                              const unsigned short* __restrict__ wqTb,
                                              const unsigned short* __restrict__ wEb,
                                              unsigned short* __restrict__ Mt,
                                              unsigned short* __restrict__ Ut) {
  __shared__ short Ss[80 * 64];
  __shared__ short Ls[256 * 64];
  int z = blockIdx.x;
  int mc = blockIdx.y;
  bool mt = z < 128;
  int zz = mt ? z : z - 128;
  int b = zz >> 4, h = zz & 15;
  const unsigned short* small_src = kvb + (size_t)b * SP_ * 2048 + (mt ? h * 64 : 1024 + h * 64);
  const unsigned short* large_src = mt ? (wqTb + h * 64) : (wEb + (size_t)2048 * 1024 + h * 64);
  int t = threadIdx.x, lane = t & 63, w = t >> 6;
  int r = lane & 15, q = lane >> 4;

  // stage both operands, then ONE barrier (drains vmcnt)
#pragma unroll
  for (int p = 0; p < 2; ++p) {
    int cb = p * 512 + w * 64;
    if (cb < 640) {
      int cc = cb + lane, row = cc >> 3, gc = (cc & 7) ^ (row & 7);
      gload16(small_src + (size_t)row * 2048 + gc * 8, (char*)Ss + cb * 16);
    }
  }
#pragma unroll
  for (int p = 0; p < 4; ++p) {
    int cb = p * 512 + w * 64;
    int cc = cb + lane, row = cc >> 3, gc = (cc & 7) ^ (row & 7);
    gload16(large_src + (size_t)(mc * 256 + row) * 1024 + gc * 8, (char*)Ls + cb * 16);
  }
  __syncthreads();

  if (mt) {
    f4 acc[5][2] = {};
#pragma unroll
    for (int kk = 0; kk < 2; ++kk) {
      int co = ((kk * 4 + q) ^ (r & 7)) * 8;
      short8 fa[5], fb[2];
#pragma unroll
      for (int mi = 0; mi < 5; ++mi)
        fa[mi] = *(const short8*)(Ss + (mi * 16 + r) * 64 + co);
#pragma unroll
      for (int ni = 0; ni < 2; ++ni)
        fb[ni] = *(const short8*)(Ls + (w * 32 + ni * 16 + r) * 64 + co);
#pragma unroll
      for (int mi = 0; mi < 5; ++mi)
#pragma unroll
        for (int ni = 0; ni < 2; ++ni)
          acc[mi][ni] = __builtin_amdgcn_mfma_f32_16x16x32_bf16(fa[mi], fb[ni], acc[mi][ni], 0, 0, 0);
    }
#pragma unroll
    for (int mi = 0; mi < 5; ++mi)
#pragma unroll
      for (int ni = 0; ni < 2; ++ni)
#pragma unroll
        for (int j = 0; j < 4; ++j) {
          int s = mi * 16 + q * 4 + j;
          int e = mc * 256 + w * 32 + ni * 16 + r;
          Mt[((size_t)b * NC_ + h * SP_ + s) * 1024 + e] = f2bf(acc[mi][ni][j] * 0.125f);
        }
  } else {
    f4 acc[2][5] = {};
#pragma unroll
    for (int kk = 0; kk < 2; ++kk) {
      int co = ((kk * 4 + q) ^ (r & 7)) * 8;
      short8 fa[2], fb[5];
#pragma unroll
      for (int mi = 0; mi < 2; ++mi)
        fa[mi] = *(const short8*)(Ls + (w * 32 + mi * 16 + r) * 64 + co);
#pragma unroll
      for (int ni = 0; ni < 5; ++ni)
        fb[ni] = *(const short8*)(Ss + (ni * 16 + r) * 64 + co);
#pragma unroll
      for (int mi = 0; mi < 2; ++mi)
#pragma unroll
        for (int ni = 0; ni < 5; ++ni)
          acc[mi][ni] = __builtin_amdgcn_mfma_f32_16x16x32_bf16(fa[mi], fb[ni], acc[mi][ni], 0, 0, 0);
    }
#pragma unroll
    for (int mi = 0; mi < 2; ++mi)
#pragma unroll
      for (int ni = 0; ni < 5; ++ni)
#pragma unroll
        for (int j = 0; j < 4; ++j) {
          int e = mc * 256 + w * 32 + mi * 16 + q * 4 + j;
          int col = h * SP_ + ni * 16 + r;
          Ut[((size_t)b * D_ + e) * NC_ + col] = f2bf(acc[mi][ni][j]);
        }
  }
}

// ---------------- mu/alpha/beta per (b,h,s) ----------------
__global__ void k_mubeta(const float* __restrict__ hssum, const float* __restrict__ Wq,
                         const unsigned short* __restrict__ kvb,
                         const int* __restrict__ sb, const int* __restrict__ sn,
                         const float* __restrict__ csf_p,
                         float* __restrict__ alphav, float* __restrict__ betav) {
  int h = blockIdx.x, b = blockIdx.y;
  int t = threadIdx.x;
  __shared__ float qp[64];
  {
    int hd = t >> 1, half = t & 1;
    const float* wr = Wq + (size_t)(h * 64 + hd) * D_ + half * 512;
    const float* hp = hssum + b * D_ + half * 512;
    float s = 0.f;
    for (int d = 0; d < 512; d += 4) {
      f4 w = *(const f4*)(wr + d);
      f4 x = *(const f4*)(hp + d);
      s += w[0] * x[0] + w[1] * x[1] + w[2] * x[2] + w[3] * x[3];
    }
    s += __shfl_xor(s, 1, 64);
    if (half == 0) qp[hd] = s * (1.f / 4096.f);
  }
  __syncthreads();
  int s = t;
  if (s >= SP_) return;
  const unsigned short* kp = kvb + ((size_t)(b * SP_ + s)) * 2048 + h * HD_;
  float mu = 0.f;
#pragma unroll
  for (int hd = 0; hd < HD_; hd += 4) {
    us4 kv = *(const us4*)(kp + hd);
#pragma unroll
    for (int j = 0; j < 4; ++j) mu += qp[hd + j] * bf2f(kv[j]);
  }
  mu *= 0.125f;
  bool subj = false;
  for (int i = 0; i < NSUBJ_; ++i) subj = subj || (sb[i] == b && sn[i] == s);
  float csf = *csf_p;
  int c = b * NC_ + h * SP_ + s;
  alphav[c] = subj ? csf : 1.f;
  betav[c] = (s >= S_) ? -1e30f : (subj ? -mu * csf : 0.f);
}

// ---------------- score GEMM 256x320 (UNCHANGED — 110us stable x9 benches) ----------------
__global__ __launch_bounds__(512, 2) void k_score_big(
    const unsigned short* __restrict__ hsb, const unsigned short* __restrict__ Mt,
    const float* __restrict__ alphav, const float* __restrict__ betav,
    unsigned short* __restrict__ P) {
  extern __shared__ short lds[];
  int id = blockIdx.x;
  int x = id & 7, idp = id >> 3;
  int nt = idp & 3;
  int pid = (idp >> 2) * 8 + x;
  int b = pid >> 4, mt = pid & 15;
  int m0 = mt * 256, n0 = nt * 320;

  const unsigned short* Ab = hsb + (size_t)b * LQ_ * D_;
  const unsigned short* Bb = Mt + (size_t)b * NC_ * D_;
  const float* alp = alphav + b * NC_;
  const float* bet = betav + b * NC_;
  unsigned short* Pb = P + (size_t)b * LQ_ * NC_;

  int t = threadIdx.x, lane = t & 63, wid = t >> 6;
  int wm = wid >> 2, wn = wid & 3;
  int r = lane & 15, q = lane >> 4;
  f4 acc[8][5] = {};

  auto SA = [&](int bf, int k0, int p) {
    int cb = p * 512 + wid * 64;
    int cc = cb + lane;
    int row = cc >> 2, gc = (cc & 3) ^ ((row >> 1) & 3);
    gload16(Ab + (size_t)(m0 + row) * D_ + k0 + gc * 8, (char*)(lds + bf * 8192) + cb * 16);
  };
  auto SB = [&](int bf, int k0, int p) {
    int cb = p * 512 + wid * 64;
    int cc = cb + lane;
    int row = cc >> 2, gc = (cc & 3) ^ ((row >> 1) & 3);
    gload16(Bb + (size_t)(n0 + row) * D_ + k0 + gc * 8, (char*)(lds + 32768 + bf * 10240) + cb * 16);
  };
  auto SBx = [&](int bf, int k0) {
    if (wid < 4) {
      int cb = 1024 + wid * 64;
      int cc = cb + lane;
      int row = cc >> 2, gc = (cc & 3) ^ ((row >> 1) & 3);
      gload16(Bb + (size_t)(n0 + row) * D_ + k0 + gc * 8, (char*)(lds + 32768 + bf * 10240) + cb * 16);
    }
  };
  auto STAGE_P1 = [&](int h) { if (h < 32) { int bf = h & 3, k0 = h * 32; SA(bf, k0, 0); SA(bf, k0, 1); SB(bf, k0, 0); } };
  auto STAGE_P2 = [&](int h) { if (h < 32) { int bf = h & 3, k0 = h * 32; SB(bf, k0, 1); SBx(bf, k0); } };

  STAGE_P1(0); STAGE_P2(0);
  STAGE_P1(1); STAGE_P2(1);
  STAGE_P1(2); STAGE_P2(2);
  if (wid < 4) asm volatile("s_waitcnt vmcnt(10)" ::: "memory");
  else         asm volatile("s_waitcnt vmcnt(8)" ::: "memory");
  __builtin_amdgcn_s_barrier();

#pragma unroll 1
  for (int h = 0; h < 32; ++h) {
    int bf = h & 3;
    const short* Ar = lds + bf * 8192;
    const short* Br = lds + 32768 + bf * 10240;
    short8 fa[4], fb[5];

#pragma unroll
    for (int ni = 0; ni < 5; ++ni) {
      int row = wn * 80 + ni * 16 + r;
      fb[ni] = *(const short8*)(Br + row * 32 + ((q ^ ((row >> 1) & 3)) * 8));
    }
#pragma unroll
    for (int mi = 0; mi < 4; ++mi) {
      int row = wm * 128 + mi * 16 + r;
      fa[mi] = *(const short8*)(Ar + row * 32 + ((q ^ ((row >> 1) & 3)) * 8));
    }
    __builtin_amdgcn_sched_barrier(0);
    STAGE_P1(h + 3);
    __builtin_amdgcn_sched_barrier(0);
    __builtin_amdgcn_s_barrier();
    asm volatile("s_waitcnt lgkmcnt(0)");
    __builtin_amdgcn_s_setprio(1);
#pragma unroll
    for (int mi = 0; mi < 4; ++mi)
#pragma unroll
      for (int ni = 0; ni < 5; ++ni)
        acc[mi][ni] = __builtin_amdgcn_mfma_f32_16x16x32_bf16(fa[mi], fb[ni], acc[mi][ni], 0, 0, 0);
    __builtin_amdgcn_s_setprio(0);

#pragma unroll
    for (int mi = 0; mi < 4; ++mi) {
      int row = wm * 128 + (4 + mi) * 16 + r;
      fa[mi] = *(const short8*)(Ar + row * 32 + ((q ^ ((row >> 1) & 3)) * 8));
    }
    __builtin_amdgcn_sched_barrier(0);
    STAGE_P2(h + 3);
    __builtin_amdgcn_sched_barrier(0);
    __builtin_amdgcn_s_barrier();
    asm volatile("s_waitcnt lgkmcnt(0)");
    __builtin_amdgcn_s_setprio(1);
#pragma unroll
    for (int mi = 0; mi < 4; ++mi)
#pragma unroll
      for (int ni = 0; ni < 5; ++ni)
        acc[4 + mi][ni] = __builtin_amdgcn_mfma_f32_16x16x32_bf16(fa[mi], fb[ni], acc[4 + mi][ni], 0, 0, 0);
    __builtin_amdgcn_s_setprio(0);

    if (h <= 28) {
      if (wid < 4) asm volatile("s_waitcnt vmcnt(10)" ::: "memory");
      else         asm volatile("s_waitcnt vmcnt(8)" ::: "memory");
    } else if (h == 29) {
      if (wid < 4) asm volatile("s_waitcnt vmcnt(5)" ::: "memory");
      else         asm volatile("s_waitcnt vmcnt(4)" ::: "memory");
    } else if (h == 30) {
      asm volatile("s_waitcnt vmcnt(0)" ::: "memory");
    }
    if (h < 31) __builtin_amdgcn_s_barrier();
  }

  float al[5], be[5];
#pragma unroll
  for (int ni = 0; ni < 5; ++ni) {
    int cc = n0 + wn * 80 + ni * 16 + r;
    al[ni] = alp[cc]; be[ni] = bet[cc];
  }
#pragma unroll
  for (int mi = 0; mi < 8; ++mi) {
#pragma unroll
    for (int j = 0; j < 4; ++j) {
      float v[5];
      float m = -3.0e38f;
#pragma unroll
      for (int ni = 0; ni < 5; ++ni) { v[ni] = acc[mi][ni][j] * al[ni] + be[ni]; m = fmaxf(m, v[ni]); }
#pragma unroll
      for (int off = 1; off < 16; off <<= 1) m = fmaxf(m, __shfl_xor(m, off, 64));
      float ssum = 0.f;
#pragma unroll
      for (int ni = 0; ni < 5; ++ni) { v[ni] = __expf(v[ni] - m); ssum += v[ni]; }
#pragma unroll
      for (int off = 1; off < 16; off <<= 1) ssum += __shfl_xor(ssum, off, 64);
      float inv = 1.f / ssum;
      int row = m0 + wm * 128 + mi * 16 + q * 4 + j;
      size_t rb = (size_t)row * NC_ + n0 + wn * 80 + r;
#pragma unroll
      for (int ni = 0; ni < 5; ++ni)
        Pb[rb + ni * 16] = f2bf(v[ni] * inv);
    }
  }
}

// ---------------- fallback score GEMM (fp32 A, reg-staged) ----------------
__global__ __launch_bounds__(256) void k_score_f32(
    const float* __restrict__ hs, const unsigned short* __restrict__ Mt,
    const float* __restrict__ alphav, const float* __restrict__ betav,
    unsigned short* __restrict__ P) {
  int id = blockIdx.x;
  int x = id & 7, idp = id >> 3;
  int n_t = idp & 7;
  int pid = (idp >> 3) * 8 + x;
  int b = pid >> 5, m_t = pid & 31;
  int m0 = m_t * 128, n0 = n_t * 160;
  const float* Af = hs + (size_t)b * LQ_ * D_;
  const unsigned short* Bb = Mt + (size_t)b * NC_ * D_;
  const float* alp = alphav + b * NC_;
  const float* bet = betav + b * NC_;
  unsigned short* Pb = P + (size_t)b * LQ_ * NC_;
  __shared__ short As[128 * 64];
  __shared__ short Bs[160 * 64];
  int t = threadIdx.x, lane = t & 63, wid = t >> 6;
  int wm = wid >> 1, wn = wid & 1;
  int srow = lane >> 3;
  int schunk = (lane & 7) ^ srow;
  f4 acc[4][5] = {};
  for (int k0 = 0; k0 < D_; k0 += 64) {
    __syncthreads();
    for (int i = wid; i < 20; i += 4)
      gload16(Bb + (size_t)(n0 + i * 8 + srow) * D_ + k0 + schunk * 8, (char*)Bs + i * 1024);
    int arow = t >> 3, ac = t & 7;
    int awc = ac ^ (arow & 7);
#pragma unroll
    for (int p = 0; p < 4; ++p) {
      int row = p * 32 + arow;
      const float* src = Af + (size_t)(m0 + row) * D_ + k0 + ac * 8;
      f4 v0 = *(const f4*)src;
      f4 v1 = *(const f4*)(src + 4);
      us8 u;
#pragma unroll
      for (int j = 0; j < 4; ++j) { u[j] = f2bf(v0[j]); u[4 + j] = f2bf(v1[j]); }
      *(us8*)(As + row * 64 + awc * 8) = u;
    }
    __syncthreads();
#pragma unroll
    for (int kk = 0; kk < 2; ++kk) {
      int co = ((kk * 4 + (lane >> 4)) ^ (lane & 7)) * 8;
      short8 fa[4], fb[5];
#pragma unroll
      for (int mi = 0; mi < 4; ++mi)
        fa[mi] = *(const short8*)(As + (wm * 64 + mi * 16 + (lane & 15)) * 64 + co);
#pragma unroll
      for (int ni = 0; ni < 5; ++ni)
        fb[ni] = *(const short8*)(Bs + (wn * 80 + ni * 16 + (lane & 15)) * 64 + co);
#pragma unroll
      for (int mi = 0; mi < 4; ++mi)
#pragma unroll
        for (int ni = 0; ni < 5; ++ni)
          acc[mi][ni] = __builtin_amdgcn_mfma_f32_16x16x32_bf16(fa[mi], fb[ni], acc[mi][ni], 0, 0, 0);
    }
  }
  float al[5], be[5];
#pragma unroll
  for (int ni = 0; ni < 5; ++ni) {
    int cc = n0 + wn * 80 + ni * 16 + (lane & 15);
    al[ni] = alp[cc]; be[ni] = bet[cc];
  }
#pragma unroll
  for (int mi = 0; mi < 4; ++mi) {
#pragma unroll
    for (int j = 0; j < 4; ++j) {
      float v[5];
      float m = -3.0e38f;
#pragma unroll
      for (int ni = 0; ni < 5; ++ni) { v[ni] = acc[mi][ni][j] * al[ni] + be[ni]; m = fmaxf(m, v[ni]); }
#pragma unroll
      for (int off = 1; off < 16; off <<= 1) m = fmaxf(m, __shfl_xor(m, off, 64));
      float ssum = 0.f;
#pragma unroll
      for (int ni = 0; ni < 5; ++ni) { v[ni] = __expf(v[ni] - m); ssum += v[ni]; }
#pragma unroll
      for (int off = 1; off < 16; off <<= 1) ssum += __shfl_xor(ssum, off, 64);
      float inv = 1.f / ssum;
      int row = m0 + wm * 64 + mi * 16 + (lane >> 4) * 4 + j;
      size_t rb = (size_t)row * NC_ + n0 + wn * 80 + (lane & 15);
#pragma unroll
      for (int ni = 0; ni < 5; ++ni)
        Pb[rb + ni * 16] = f2bf(v[ni] * inv);
    }
  }
}

// ---------------- out GEMM 256x256 (UNCHANGED) ----------------
__global__ __launch_bounds__(512, 2) void k_out_big(
    const unsigned short* __restrict__ P, const unsigned short* __restrict__ Ut,
    const float* __restrict__ bo, float* __restrict__ out) {
  extern __shared__ short lds[];
  int id = blockIdx.x;
  int x = id & 7, idp = id >> 3;
  int nt = idp & 3;
  int pid = (idp >> 2) * 8 + x;
  int b = pid >> 4, mt = pid & 15;
  int m0 = mt * 256, n0 = nt * 256;

  const unsigned short* Ab = P + (size_t)b * LQ_ * NC_;
  const unsigned short* Bb = Ut + (size_t)b * D_ * NC_;
  float* ob = out + (size_t)b * LQ_ * D_;

  int t = threadIdx.x, lane = t & 63, wid = t >> 6;
  int wm = wid >> 2, wn = wid & 3;
  int r = lane & 15, q = lane >> 4;
  f4 acc[8][4] = {};
  const int T = NC_ / 32;   // 40

  auto SA = [&](int bf, int k0, int p) {
    int cb = p * 512 + wid * 64;
    int cc = cb + lane;
    int row = cc >> 2, gc = (cc & 3) ^ ((row >> 1) & 3);
    gload16(Ab + (size_t)(m0 + row) * NC_ + k0 + gc * 8, (char*)(lds + bf * 8192) + cb * 16);
  };
  auto SB = [&](int bf, int k0, int p) {
    int cb = p * 512 + wid * 64;
    int cc = cb + lane;
    int row = cc >> 2, gc = (cc & 3) ^ ((row >> 1) & 3);
    gload16(Bb + (size_t)(n0 + row) * NC_ + k0 + gc * 8, (char*)(lds + 32768 + bf * 8192) + cb * 16);
  };
  auto STAGE_P1 = [&](int h) { if (h < T) { int bf = h & 3, k0 = h * 32; SA(bf, k0, 0); SA(bf, k0, 1); } };
  auto STAGE_P2 = [&](int h) { if (h < T) { int bf = h & 3, k0 = h * 32; SB(bf, k0, 0); SB(bf, k0, 1); } };

  STAGE_P1(0); STAGE_P2(0);
  STAGE_P1(1); STAGE_P2(1);
  STAGE_P1(2); STAGE_P2(2);
  asm volatile("s_waitcnt vmcnt(8)" ::: "memory");
  __builtin_amdgcn_s_barrier();

#pragma unroll 1
  for (int h = 0; h < T; ++h) {
    int bf = h & 3;
    const short* Ar = lds + bf * 8192;
    const short* Br = lds + 32768 + bf * 8192;
    short8 fa[4], fb[4];

#pragma unroll
    for (int ni = 0; ni < 4; ++ni) {
      int row = wn * 64 + ni * 16 + r;
      fb[ni] = *(const short8*)(Br + row * 32 + ((q ^ ((row >> 1) & 3)) * 8));
    }
#pragma unroll
    for (int mi = 0; mi < 4; ++mi) {
      int row = wm * 128 + mi * 16 + r;
      fa[mi] = *(const short8*)(Ar + row * 32 + ((q ^ ((row >> 1) & 3)) * 8));
    }
    __builtin_amdgcn_sched_barrier(0);
    STAGE_P1(h + 3);
    __builtin_amdgcn_sched_barrier(0);
    __builtin_amdgcn_s_barrier();
    asm volatile("s_waitcnt lgkmcnt(0)");
    __builtin_amdgcn_s_setprio(1);
#pragma unroll
    for (int mi = 0; mi < 4; ++mi)
#pragma unroll
      for (int ni = 0; ni < 4; ++ni)
        acc[mi][ni] = __builtin_amdgcn_mfma_f32_16x16x32_bf16(fa[mi], fb[ni], acc[mi][ni], 0, 0, 0);
    __builtin_amdgcn_s_setprio(0);

#pragma unroll
    for (int mi = 0; mi < 4; ++mi) {
      int row = wm * 128 + (4 + mi) * 16 + r;
      fa[mi] = *(const short8*)(Ar + row * 32 + ((q ^ ((row >> 1) & 3)) * 8));
    }
    __builtin_amdgcn_sched_barrier(0);
    STAGE_P2(h + 3);
    __builtin_amdgcn_sched_barrier(0);
    __builtin_amdgcn_s_barrier();
    asm volatile("s_waitcnt lgkmcnt(0)");
    __builtin_amdgcn_s_setprio(1);
#pragma unroll
    for (int mi = 0; mi < 4; ++mi)
#pragma unroll
      for (int ni = 0; ni < 4; ++ni)
        acc[4 + mi][ni] = __builtin_amdgcn_mfma_f32_16x16x32_bf16(fa[mi], fb[ni], acc[4 + mi][ni], 0, 0, 0);
    __builtin_amdgcn_s_setprio(0);

    if (h <= T - 4) {
      asm volatile("s_waitcnt vmcnt(8)" ::: "memory");
    } else if (h == T - 3) {
      asm volatile("s_waitcnt vmcnt(4)" ::: "memory");
    } else if (h == T - 2) {
      asm volatile("s_waitcnt vmcnt(0)" ::: "memory");
    }
    if (h < T - 1) __builtin_amdgcn_s_barrier();
  }

#pragma unroll
  for (int ni = 0; ni < 4; ++ni) {
    int col = n0 + wn * 64 + ni * 16 + r;
    float bov = bo[col];
#pragma unroll
    for (int mi = 0; mi < 8; ++mi)
#pragma unroll
      for (int j = 0; j < 4; ++j) {
        int row = m0 + wm * 128 + mi * 16 + q * 4 + j;
        ob[(size_t)row * D_ + col] = acc[mi][ni][j] + bov;
      }
  }
}

extern "C" void kernel_launch(void* const* d_in, const int* in_sizes, int n_in,
                              void* d_out, int out_size, void* d_ws, size_t ws_size,
                              hipStream_t stream) {
  const float* hs  = (const float*)d_in[0];
  const float* ehs = (const float*)d_in[1];
  const float* Wq  = (const float*)d_in[2];
  const float* Wk  = (const float*)d_in[3];
  const float* Wv  = (const float*)d_in[4];
  const float* Wo  = (const float*)d_in[5];
  const float* bo  = (const float*)d_in[6];
  const float* Ak  = (const float*)d_in[7];
  const float* Bk  = (const float*)d_in[8];
  const float* Av  = (const float*)d_in[9];
  const float* Bv  = (const float*)d_in[10];
  const float* Ao  = (const float*)d_in[11];
  const float* Bo  = (const float*)d_in[12];
  const float* csf = (const float*)d_in[13];
  const int*   sb  = (const int*)d_in[14];
  const int*   sn  = (const int*)d_in[15];
  float* out = (float*)d_out;

  hipFuncSetAttribute(reinterpret_cast<const void*>(k_score_big),
                      hipFuncAttributeMaxDynamicSharedMemorySize, 147456);
  hipFuncSetAttribute(reinterpret_cast<const void*>(k_out_big),
                      hipFuncAttributeMaxDynamicSharedMemorySize, 131072);

  char* ws = (char*)d_ws;
  unsigned short* P  = (unsigned short*)ws;                   // 83,886,080
  unsigned short* Mt = (unsigned short*)(ws + 83886080);      // 20,971,520
  unsigned short* Ut = (unsigned short*)(ws + 104857600);     // 20,971,520
  const size_t NEED_HSB = 125829120ULL + 67108864ULL + 81920ULL; // 193,019,904
  bool useHsb = ws_size >= NEED_HSB;
  unsigned short* hsb = useHsb ? (unsigned short*)(ws + 125829120) : nullptr;
  char* tail = useHsb ? (ws + 192937984) : (ws + 125829120);
  float* alphav = (float*)tail;
  float* betav  = (float*)(tail + 40960);
  // temporaries overlapped into P's region (all dead before k_score writes P):
  unsigned short* kvb   = (unsigned short*)(ws + 0);          //  2,621,440
  unsigned short* wEb   = (unsigned short*)(ws + 2621440);    //  6,291,456
  unsigned short* wqTb  = (unsigned short*)(ws + 8912896);    //  2,097,152
  unsigned short* aTb   = (unsigned short*)(ws + 11010048);   //  1,179,648
  unsigned short* bxb   = (unsigned short*)(ws + 12189696);   //  1,179,648
  unsigned short* ehsb  = (unsigned short*)(ws + 13369344);   //  1,310,720
  float*          part  = (float*)(ws + 14680064);            //  2,097,152
  float*          hssum = (float*)(ws + 16777216);            //     32,768

  const float LS = 16.0f / 192.0f;

  // hs row-sums (deterministic two-stage) + bf16 conversion of hs
  k_hssum<<<dim3(64, 8), 256, 0, stream>>>(hs, part, hsb);
  k_hsred<<<32, 256, 0, stream>>>(part, hssum);

  // all conversions/transposes in one launch
  k_prep<<<dim3(32, 32, 8), 256, 0, stream>>>(Wq, Ak, Av, Ao, ehs, Bk, Bv, Bo,
                                              wqTb, aTb, ehsb, bxb);

  // W_eff (k,v,o) via proper bf16 GEMM
  k_weff_big<<<dim3(8, 8, 3), 256, 0, stream>>>(bxb, aTb, Wk, Wv, Wo, wEb, LS);

  // kv = ehsb @ wEb[k|v]^T  (bf16, 256 blocks, double-buffered)
  k_kv<<<256, 256, 0, stream>>>(ehsb, wEb, kvb);

  // Mt + Ut panels: (b,h) x mc chunk, 1024 blocks
  k_mtut<<<dim3(256, 4), 512, 0, stream>>>(kvb, wqTb, wEb, Mt, Ut);

  // per-(b,h,s) column mean (qmean fused) + subject alpha/beta
  k_mubeta<<<dim3(16, 8), 128, 0, stream>>>(hssum, Wq, kvb, sb, sn, csf, alphav, betav);

  // big fused GEMMs (proven stable versions)
  if (useHsb)
    k_score_big<<<512, 512, 147456, stream>>>(hsb, Mt, alphav, betav, P);
  else
    k_score_f32<<<2048, 256, 0, stream>>>(hs, Mt, alphav, betav, P);
  k_out_big<<<512, 512, 131072, stream>>>(P, Ut, bo, out);

  (void)in_sizes; (void)n_in; (void)out_size; (void)ws_size;
}